// Round 8
// baseline (238.959 us; speedup 1.0000x reference)
//
#include <hip/hip_runtime.h>

typedef unsigned int u32;
typedef unsigned short u16;
typedef unsigned long long u64;
typedef __attribute__((ext_vector_type(8))) short bf16x8;   // 8 bf16 in 4 VGPRs
typedef __attribute__((ext_vector_type(4))) float f32x4;

#define NPTS 4096
#define DIM  64
#define NB   32          // 4096/128
#define NBLK 528         // NB*(NB+1)/2 upper-tri 128x128 blocks
#define WLO16 0x4140u    // window low: float bits 0x41400000 = 12.0
#define NWBIN 832        // t16 in [0x4140, 0x4480) -> D in [12, 1024)
#define RSTR 836         // histogram stride in u32 (834 bins + pad)
#define LOG2E 1.4426950408889634f
// full-matrix ranks: diag(4096 zeros) + doubled upper-tri; m_ut = 8386560
#define KF1C 8390654u
#define KF2C 8390656u

// map linear upper-tri block id -> (by,bx), bx>=by
__device__ __forceinline__ void bmap(int b, int& by, int& bx){
  by = 0;
  while (b >= NB - by){ b -= NB - by; by++; }
  bx = by + b;
}

// fp32 -> bf16 bits, round-nearest-even
__device__ __forceinline__ u16 f2bf(float x){
  u32 u = __float_as_uint(x);
  return (u16)((u + 0x7fffu + ((u>>16)&1u)) >> 16);
}

// bare v_exp_f32 (args bounded in [-5,0])
__device__ __forceinline__ float fexp2(float x){
  return __builtin_amdgcn_exp2f(x);
}

// agent-scope coherent helpers (bypass per-XCD L2 staleness)
__device__ __forceinline__ u32 aload_u32(const u32* p){
  return __hip_atomic_load((u32*)p, __ATOMIC_RELAXED, __HIP_MEMORY_SCOPE_AGENT);
}
__device__ __forceinline__ double aload_f64(const double* p){
  return __hip_atomic_load((double*)p, __ATOMIC_RELAXED, __HIP_MEMORY_SCOPE_AGENT);
}
__device__ __forceinline__ void astore_u64(u64* p, u64 v){
  __hip_atomic_store(p, v, __ATOMIC_RELAXED, __HIP_MEMORY_SCOPE_AGENT);
}
__device__ __forceinline__ void astore_f32(float* p, float v){
  __hip_atomic_store(p, v, __ATOMIC_RELAXED, __HIP_MEMORY_SCOPE_AGENT);
}

// monotone-counter grid barrier: arrive (device-scope RMW) + acquire-spin.
// Counter never resets; phase k waits for ctr >= k*gsz. Co-residency is
// guaranteed by hipLaunchCooperativeKernel.
__device__ __forceinline__ void gbarrier(u32* bar, u32 target){
  __syncthreads();                 // all block threads done; vmcnt drained (atomics complete)
  if (threadIdx.x == 0){
    __hip_atomic_fetch_add(bar, 1u, __ATOMIC_ACQ_REL, __HIP_MEMORY_SCOPE_AGENT);
    while (__hip_atomic_load(bar, __ATOMIC_ACQUIRE, __HIP_MEMORY_SCOPE_AGENT) < target)
      __builtin_amdgcn_s_sleep(8);
  }
  __syncthreads();
}

// ---------- block-parallel gamma series: 1024 terms/batch (4 per thread) ----------
__device__ double gammainc_block4(double a, double x, double lga,
                                  int tid, int lane, int w,
                                  double* wp /*shared[4]*/, double* bs /*shared[4]*/){
  double C = 1.0/a;
  double psum = 0.0;
  for (int b=0;b<512;b++){
    double k0 = (double)(b*1024 + tid*4);
    double r1 = x/(a+k0+1.0), r2 = x/(a+k0+2.0), r3 = x/(a+k0+3.0), r4 = x/(a+k0+4.0);
    double p12 = r1*r2;
    double pl = p12*(r3*r4);
    double pp = pl;
#pragma unroll
    for (int s=1;s<64;s<<=1){
      double t = __shfl_up(pp, s, 64);
      if (lane >= s) pp *= t;
    }
    if (lane==63) wp[w] = pp;
    __syncthreads();
    double cross = 1.0;
    for (int k2=0;k2<w;k2++) cross *= wp[k2];
    double call = wp[0]*wp[1]*wp[2]*wp[3];
    double excl = __shfl_up(pp, 1, 64);
    if (lane==0) excl = 1.0;
    double base = C*cross*excl;
    double t1 = base*r1, t2 = base*p12, t3 = t2*r3, t4 = base*pl;
    psum += (t1+t2)+(t3+t4);
    double Cn = C*call;
    C = Cn;
    double rlast = x/(a + (double)(b*1024 + 1024));
    __syncthreads();
    if (rlast < 1.0 && Cn*rlast/(1.0-rlast) < 1e-17) break;
  }
#pragma unroll
  for (int s=1;s<64;s<<=1) psum += __shfl_xor(psum, s, 64);
  if (lane==0) bs[w] = psum;
  __syncthreads();
  double total = 1.0/a + bs[0]+bs[1]+bs[2]+bs[3];
  __syncthreads();
  return exp(-x + a*log(x) - lga) * total;
}

// ===================== fused persistent kernel: all phases, hand-rolled barriers =====================
__global__ __launch_bounds__(256) void hsic_fused(
    const float* __restrict__ X, const float* __restrict__ Y,
    u16* __restrict__ Xbf, float* __restrict__ Gall,
    u32* __restrict__ histsum, double* __restrict__ rowK, double* __restrict__ rowL,
    double* __restrict__ sumsS, double* __restrict__ slotbuf, u32* __restrict__ ctr,
    float* __restrict__ out)
{
  const int tid = threadIdx.x;
  const int bid = blockIdx.x;
  const int gsz = gridDim.x;
  const int w = tid>>6, lane = tid&63, q = lane>>4, nl = lane&15;
  const int gtid = bid*256 + tid;
  const int gstr = gsz*256;

  __shared__ union {
    struct { u32 lh[4][RSTR]; bf16x8 sB[1024]; } h;                       // hist: 29.4 KB
    struct {
      union {
        struct { u32 wsum[4]; double svals[2]; float scal_sh; } sc;
        struct { double rowacc[128]; double colLDS[4][128]; double tred[2]; } rs;
      } u;
      bf16x8 sB[1024];
    } r;                                                                  // scan/rowsum: 21.5 KB
    struct { bf16x8 sBX[1024]; bf16x8 sBY[1024]; double red[4][3];
             double gwp[4]; double gbs[4]; double stot[3]; double s16[16];
             int lastFlag; } f;                                           // final: 33 KB
  } sh;

  // ---------------- P0: convert to swizzled bf16 + norms (agent-coherent stores) ----------------
  for (int t = gtid; t < 4*NPTS; t += gstr){
    int rid = t >> 1, hf = t & 1;
    int z = rid >> 12, row = rid & 4095;
    const float* src = (z ? Y : X) + (size_t)row*DIM + hf*32;
    u16* basep = Xbf + ((size_t)z*32768 + (size_t)(row>>4)*128 + (row&15))*8;
    float g = 0.f;
#pragma unroll
    for (int f=0; f<4; f++){
      float4 f0 = *(const float4*)(src + f*8);
      float4 f1 = *(const float4*)(src + f*8 + 4);
      g = fmaf(f0.x,f0.x,g); g = fmaf(f0.y,f0.y,g); g = fmaf(f0.z,f0.z,g); g = fmaf(f0.w,f0.w,g);
      g = fmaf(f1.x,f1.x,g); g = fmaf(f1.y,f1.y,g); g = fmaf(f1.z,f1.z,g); g = fmaf(f1.w,f1.w,g);
      union { ushort4 s; u64 qv; } c0, c1;
      c0.s.x=f2bf(f0.x); c0.s.y=f2bf(f0.y); c0.s.z=f2bf(f0.z); c0.s.w=f2bf(f0.w);
      c1.s.x=f2bf(f1.x); c1.s.y=f2bf(f1.y); c1.s.z=f2bf(f1.z); c1.s.w=f2bf(f1.w);
      u16* dst = basep + (size_t)(hf*4 + f)*16*8;
      astore_u64((u64*)dst, c0.qv);
      astore_u64((u64*)(dst+4), c1.qv);
    }
    g += __shfl_xor(g, 1, 64);
    if (hf==0) astore_f32(&Gall[rid], g);
  }
  gbarrier(ctr, (u32)gsz);

  // ---------------- P1: upper-tri block histogram (x2 off-diag), LDS-staged B ----------------
  for (int tile = bid; tile < 2*NBLK; tile += gsz){
    int z = (tile >= NBLK) ? 1 : 0;
    int b = tile - (z ? NBLK : 0);
    int by,bx; bmap(b,by,bx);
    bool isdiag = (by==bx);
    u32 wgt = isdiag ? 1u : 2u;
    int cp = lane & 3;
    const bf16x8* Xb = (const bf16x8*)Xbf + (size_t)z*32768;
    const bf16x8* srcB = Xb + (size_t)(bx*8)*128;
    for (int t=tid;t<1024;t+=256) sh.h.sB[t] = srcB[t];
    for (int t=tid;t<4*RSTR;t+=256) ((u32*)sh.h.lh)[t]=0;
    __syncthreads();
    const float* Gz = Gall + z*NPTS;
    int ag0 = by*8 + w, ag1 = by*8 + 4 + w;
    bf16x8 a0f0 = Xb[ag0*128 + q*16 + nl];
    bf16x8 a0f1 = Xb[ag0*128 + (4+q)*16 + nl];
    bf16x8 a1f0 = Xb[ag1*128 + q*16 + nl];
    bf16x8 a1f1 = Xb[ag1*128 + (4+q)*16 + nl];
    float ga0 = Gz[ag0*16 + nl], ga1 = Gz[ag1*16 + nl];
    float g0m[4], g1m[4];
#pragma unroll
    for (int r=0;r<4;r++){ g0m[r] = __shfl(ga0, q*4+r, 64); g1m[r] = __shfl(ga1, q*4+r, 64); }
#pragma unroll
    for (int tb=0;tb<8;tb++){
      bf16x8 bf0 = sh.h.sB[tb*128 + q*16 + nl];
      bf16x8 bf1 = sh.h.sB[tb*128 + (4+q)*16 + nl];
      f32x4 acc0 = (f32x4)0.0f, acc1 = (f32x4)0.0f;
      acc0 = __builtin_amdgcn_mfma_f32_16x16x32_bf16(a0f0, bf0, acc0, 0,0,0);
      acc0 = __builtin_amdgcn_mfma_f32_16x16x32_bf16(a0f1, bf1, acc0, 0,0,0);
      acc1 = __builtin_amdgcn_mfma_f32_16x16x32_bf16(a1f0, bf0, acc1, 0,0,0);
      acc1 = __builtin_amdgcn_mfma_f32_16x16x32_bf16(a1f1, bf1, acc1, 0,0,0);
      int j = (bx*8 + tb)*16 + nl;
      float gb = Gz[j];
#pragma unroll
      for (int r=0;r<4;r++){
        float d0 = (g0m[r] + gb) - 2.0f*acc0[r];
        float d1 = (g1m[r] + gb) - 2.0f*acc1[r];
        if (isdiag){
          if (ag0*16 + q*4 + r == j) d0 = 0.f;
          if (ag1*16 + q*4 + r == j) d1 = 0.f;
        }
        u32 t0 = __float_as_uint(d0) >> 16;
        u32 bin0 = (t0 < WLO16) ? 0u : (t0 >= WLO16+NWBIN) ? (u32)(NWBIN+1) : (t0 - WLO16 + 1u);
        atomicAdd(&sh.h.lh[cp][bin0], wgt);
        u32 t1 = __float_as_uint(d1) >> 16;
        u32 bin1 = (t1 < WLO16) ? 0u : (t1 >= WLO16+NWBIN) ? (u32)(NWBIN+1) : (t1 - WLO16 + 1u);
        atomicAdd(&sh.h.lh[cp][bin1], wgt);
      }
    }
    __syncthreads();
    u32* dst = histsum + (size_t)z*RSTR;
    for (int t=tid;t<RSTR;t+=256){
      u32 v = sh.h.lh[0][t] + sh.h.lh[1][t] + sh.h.lh[2][t] + sh.h.lh[3][t];
      if (v){
        u32 old = atomicAdd(&dst[t], v);     // returning form: completes before barrier drain
        asm volatile("" :: "v"(old));
      }
    }
    __syncthreads();                          // flush done before next tile restages LDS
  }
  gbarrier(ctr, (u32)(2*gsz));

  // ---------------- P2: per-block median scan (both z) -> scalz in registers ----------------
  float scalz[2];
  for (int z=0; z<2; ++z){
    u32 c4[4] = {0,0,0,0};
    if (tid < 209){
      const u32* base = histsum + (size_t)z*RSTR + 4*tid;
      int lim = RSTR - 4*tid;
      c4[0] = aload_u32(base+0);
      if (lim>1) c4[1] = aload_u32(base+1);
      if (lim>2) c4[2] = aload_u32(base+2);
      if (lim>3) c4[3] = aload_u32(base+3);
    }
    u32 s = c4[0]+c4[1]+c4[2]+c4[3];
    u32 pre = s;
#pragma unroll
    for (int off=1; off<64; off<<=1){
      u32 t2 = __shfl_up(pre, off, 64);
      if (lane >= off) pre += t2;
    }
    if (lane==63) sh.r.u.sc.wsum[w] = pre;
    __syncthreads();
    u32 base2 = 0;
    for (int k=0;k<w;k++) base2 += sh.r.u.sc.wsum[k];
    u32 incl = base2 + pre, excl = incl - s;
    u32 ks[2] = {KF1C,KF2C};
#pragma unroll
    for (int w2=0; w2<2; w2++){
      if (ks[w2] >= excl && ks[w2] < incl){
        u32 acc = excl;
#pragma unroll
        for (int j=0;j<4;j++){
          if (ks[w2] < acc + c4[j]){
            int b = tid*4 + j;
            double lo, hi;
            if (b==0){ lo=12.0; hi=12.0; }
            else if (b>=NWBIN+1){ lo=1024.0; hi=1024.0; }
            else {
              u32 t16 = WLO16 + (u32)b - 1u;
              lo = (double)__uint_as_float(t16<<16);
              hi = (double)__uint_as_float((t16+1u)<<16);
            }
            double frac = ((double)(ks[w2]-acc) + 0.5)/(double)c4[j];
            sh.r.u.sc.svals[w2] = lo + (hi-lo)*frac;
            break;
          }
          acc += c4[j];
        }
      }
    }
    __syncthreads();
    if (tid==0){
      float med = (float)(0.5*(sh.r.u.sc.svals[0]+sh.r.u.sc.svals[1]));
      float wd = sqrtf(0.5f*med);
      sh.r.u.sc.scal_sh = 2.0f*wd*wd;
    }
    __syncthreads();
    scalz[z] = sh.r.u.sc.scal_sh;
    __syncthreads();
  }

  // ---------------- P3: upper-tri block row sums (row + col via symmetry) ----------------
  for (int tile = bid; tile < 2*NBLK; tile += gsz){
    int z = (tile >= NBLK) ? 1 : 0;
    int b = tile - (z ? NBLK : 0);
    int by,bx; bmap(b,by,bx);
    bool isdiag = (by==bx);
    const bf16x8* Xb = (const bf16x8*)Xbf + (size_t)z*32768;
    const bf16x8* srcB = Xb + (size_t)(bx*8)*128;
    for (int t=tid;t<1024;t+=256) sh.r.sB[t] = srcB[t];
    __syncthreads();
    const float* Gz = Gall + z*NPTS;
    float negi = -LOG2E / scalz[z];
    int ag0 = by*8 + w, ag1 = by*8 + 4 + w;
    bf16x8 a0f0 = Xb[ag0*128 + q*16 + nl];
    bf16x8 a0f1 = Xb[ag0*128 + (4+q)*16 + nl];
    bf16x8 a1f0 = Xb[ag1*128 + q*16 + nl];
    bf16x8 a1f1 = Xb[ag1*128 + (4+q)*16 + nl];
    float ga0 = Gz[ag0*16 + nl], ga1 = Gz[ag1*16 + nl];
    float g0m[4], g1m[4];
#pragma unroll
    for (int r=0;r<4;r++){ g0m[r] = __shfl(ga0, q*4+r, 64); g1m[r] = __shfl(ga1, q*4+r, 64); }
    float rs0[4] = {0,0,0,0}, rs1[4] = {0,0,0,0};
#pragma unroll
    for (int tb=0;tb<8;tb++){
      bf16x8 bf0 = sh.r.sB[tb*128 + q*16 + nl];
      bf16x8 bf1 = sh.r.sB[tb*128 + (4+q)*16 + nl];
      f32x4 acc0 = (f32x4)0.0f, acc1 = (f32x4)0.0f;
      acc0 = __builtin_amdgcn_mfma_f32_16x16x32_bf16(a0f0, bf0, acc0, 0,0,0);
      acc0 = __builtin_amdgcn_mfma_f32_16x16x32_bf16(a0f1, bf1, acc0, 0,0,0);
      acc1 = __builtin_amdgcn_mfma_f32_16x16x32_bf16(a1f0, bf0, acc1, 0,0,0);
      acc1 = __builtin_amdgcn_mfma_f32_16x16x32_bf16(a1f1, bf1, acc1, 0,0,0);
      int j = (bx*8 + tb)*16 + nl;
      float gb = Gz[j];
      float cs = 0.f;
#pragma unroll
      for (int r=0;r<4;r++){
        float d0 = (g0m[r] + gb) - 2.0f*acc0[r];
        float d1 = (g1m[r] + gb) - 2.0f*acc1[r];
        if (isdiag){
          if (ag0*16 + q*4 + r == j) d0 = 0.f;
          if (ag1*16 + q*4 + r == j) d1 = 0.f;
        }
        float e0 = fexp2(d0*negi);
        float e1 = fexp2(d1*negi);
        rs0[r] += e0; rs1[r] += e1;
        cs += e0 + e1;
      }
      cs += __shfl_xor(cs, 16, 64);
      cs += __shfl_xor(cs, 32, 64);
      if (q==0) sh.r.u.rs.colLDS[w][tb*16 + nl] = (double)cs;
    }
#pragma unroll
    for (int r=0;r<4;r++){
      float v0 = rs0[r], v1 = rs1[r];
      v0 += __shfl_xor(v0,1,64); v0 += __shfl_xor(v0,2,64);
      v0 += __shfl_xor(v0,4,64); v0 += __shfl_xor(v0,8,64);
      v1 += __shfl_xor(v1,1,64); v1 += __shfl_xor(v1,2,64);
      v1 += __shfl_xor(v1,4,64); v1 += __shfl_xor(v1,8,64);
      rs0[r] = v0; rs1[r] = v1;
    }
    if (nl==0){
#pragma unroll
      for (int r=0;r<4;r++){
        sh.r.u.rs.rowacc[w*16 + q*4 + r]     = (double)rs0[r];
        sh.r.u.rs.rowacc[(4+w)*16 + q*4 + r] = (double)rs1[r];
      }
    }
    __syncthreads();
    double tot = 0.0;
    if (tid < 128){
      double rv = sh.r.u.rs.rowacc[tid];
      double cv = sh.r.u.rs.colLDS[0][tid] + sh.r.u.rs.colLDS[1][tid]
                + sh.r.u.rs.colLDS[2][tid] + sh.r.u.rs.colLDS[3][tid];
      double* rowG = z ? rowL : rowK;
      double o1 = atomicAdd(&rowG[by*128 + tid], rv);
      asm volatile("" :: "v"(o1));
      if (!isdiag){
        double o2 = atomicAdd(&rowG[bx*128 + tid], cv);
        asm volatile("" :: "v"(o2));
      }
      tot = rv + (isdiag ? 0.0 : cv);
    }
#pragma unroll
    for (int s2=1;s2<64;s2<<=1) tot += __shfl_xor(tot, s2, 64);
    if (lane==0 && w<2) sh.r.u.rs.tred[w] = tot;
    __syncthreads();
    if (tid==0){
      double o3 = atomicAdd(&sumsS[z*8 + (b & 7)], sh.r.u.rs.tred[0] + sh.r.u.rs.tred[1]);
      asm volatile("" :: "v"(o3));
    }
    __syncthreads();
  }
  gbarrier(ctr, (u32)(3*gsz));

  // ---------------- P4: centered products (half-tiles), accumulate across tiles ----------------
  {
    const bf16x8* Xb = (const bf16x8*)Xbf;
    const bf16x8* Yb = Xb + 32768;
    const float* Gx = Gall;
    const float* Gy = Gall + NPTS;
    const double inv_n = 1.0/(double)NPTS;
    // sums via agent loads -> shared -> broadcast
    if (tid < 16) sh.f.s16[tid] = aload_f64(&sumsS[tid]);
    __syncthreads();
    double sK=0.0, sL=0.0;
#pragma unroll
    for (int k2=0;k2<8;k2++){ sK += sh.f.s16[k2]; sL += sh.f.s16[8+k2]; }
    __syncthreads();
    double tmK = sK*(inv_n*inv_n), tmL = sL*(inv_n*inv_n);
    float negx = -LOG2E/scalz[0], negy = -LOG2E/scalz[1];
    double S1d=0.0, S2d=0.0, trVd=0.0;
    for (int t = bid; t < 2*NBLK; t += gsz){
      int b = t >> 1, half = t & 1;
      int by,bx; bmap(b,by,bx);
      bool isdiag = (by==bx);
      const bf16x8* srcBX = Xb + (size_t)(bx*8)*128;
      const bf16x8* srcBY = Yb + (size_t)(bx*8)*128;
      for (int tt=tid;tt<1024;tt+=256){ sh.f.sBX[tt] = srcBX[tt]; sh.f.sBY[tt] = srcBY[tt]; }
      float S1f=0.f, S2f=0.f, trVf=0.f;
      int ag = by*8 + half*4 + w;
      bf16x8 axf0 = Xb[ag*128 + q*16 + nl];
      bf16x8 axf1 = Xb[ag*128 + (4+q)*16 + nl];
      bf16x8 ayf0 = Yb[ag*128 + q*16 + nl];
      bf16x8 ayf1 = Yb[ag*128 + (4+q)*16 + nl];
      float gaX = Gx[ag*16 + nl], gaY = Gy[ag*16 + nl];
      float gXm[4], gYm[4];
#pragma unroll
      for (int r=0;r<4;r++){ gXm[r] = __shfl(gaX, q*4+r, 64); gYm[r] = __shfl(gaY, q*4+r, 64); }
      float rmKi[4], rmLi[4];
#pragma unroll
      for (int r=0;r<4;r++){
        int i = ag*16 + q*4 + r;
        rmKi[r] = (float)(aload_f64(&rowK[i])*inv_n);
        rmLi[r] = (float)(aload_f64(&rowL[i])*inv_n);
      }
      __syncthreads();                        // panels staged
#pragma unroll
      for (int tb=0;tb<8;tb++){
        bf16x8 bx0 = sh.f.sBX[tb*128 + q*16 + nl];
        bf16x8 bx1 = sh.f.sBX[tb*128 + (4+q)*16 + nl];
        bf16x8 by0 = sh.f.sBY[tb*128 + q*16 + nl];
        bf16x8 by1 = sh.f.sBY[tb*128 + (4+q)*16 + nl];
        f32x4 accX = (f32x4)0.0f, accY = (f32x4)0.0f;
        accX = __builtin_amdgcn_mfma_f32_16x16x32_bf16(axf0, bx0, accX, 0,0,0);
        accX = __builtin_amdgcn_mfma_f32_16x16x32_bf16(axf1, bx1, accX, 0,0,0);
        accY = __builtin_amdgcn_mfma_f32_16x16x32_bf16(ayf0, by0, accY, 0,0,0);
        accY = __builtin_amdgcn_mfma_f32_16x16x32_bf16(ayf1, by1, accY, 0,0,0);
        int j = (bx*8 + tb)*16 + nl;
        float gbX = Gx[j], gbY = Gy[j];
        float cmK = (float)(aload_f64(&rowK[j])*inv_n - tmK);
        float cmL = (float)(aload_f64(&rowL[j])*inv_n - tmL);
#pragma unroll
        for (int r=0;r<4;r++){
          int i = ag*16 + q*4 + r;
          float dx = (gXm[r] + gbX) - 2.0f*accX[r];
          float dy = (gYm[r] + gbY) - 2.0f*accY[r];
          bool dg = isdiag && i==j;
          if (dg){ dx = 0.f; dy = 0.f; }
          float kx = fexp2(dx*negx);
          float lv = fexp2(dy*negy);
          float kc = (kx - rmKi[r]) - cmK;
          float lc = (lv - rmLi[r]) - cmL;
          float prod = kc*lc;
          S1f += prod;
          S2f = fmaf(prod, prod, S2f);
          if (dg) trVf = fmaf(prod, prod, trVf);
        }
      }
      {
        double wgt = isdiag ? 1.0 : 2.0;
        S1d += wgt*(double)S1f;
        S2d += (wgt*(1.0/36.0))*(double)S2f;
        trVd += (1.0/36.0)*(double)trVf;
      }
      __syncthreads();                        // done reading panels before next restage
    }
    double vals[3]={S1d,S2d,trVd};
#pragma unroll
    for (int v=0;v<3;v++){
      double x = vals[v];
#pragma unroll
      for (int s2=1;s2<64;s2<<=1) x += __shfl_xor(x, s2, 64);
      if (lane==0) sh.f.red[w][v]=x;
    }
    __syncthreads();
    if (tid < 3){
      double val = sh.f.red[0][tid]+sh.f.red[1][tid]+sh.f.red[2][tid]+sh.f.red[3][tid];
      double old = atomicAdd(&slotbuf[(size_t)(bid & 15)*4 + tid], val);
      asm volatile("" :: "v"(old));
    }
    __syncthreads();                          // slot adds complete before ctr bump
    if (tid==0){
      u32 old = __hip_atomic_fetch_add(ctr, 1u, __ATOMIC_ACQ_REL, __HIP_MEMORY_SCOPE_AGENT);
      sh.f.lastFlag = (old == (u32)(4*gsz - 1)) ? 1 : 0;
    }
    __syncthreads();
    if (!sh.f.lastFlag) return;

    // ---- tail block: reduce slots + gamma-ppf ----
    if (w==0){
      double t0=0.0, t1=0.0, t2=0.0;
      if (lane < 16){
        double* sp = slotbuf + (size_t)lane*4;
        t0 = atomicAdd(&sp[0], 0.0);
        t1 = atomicAdd(&sp[1], 0.0);
        t2 = atomicAdd(&sp[2], 0.0);
      }
#pragma unroll
      for (int s2=1;s2<16;s2<<=1){
        t0 += __shfl_xor(t0, s2, 64);
        t1 += __shfl_xor(t1, s2, 64);
        t2 += __shfl_xor(t2, s2, 64);
      }
      if (lane==0){ sh.f.stot[0]=t0; sh.f.stot[1]=t1; sh.f.stot[2]=t2; }
    }
    __syncthreads();
    const double n = (double)NPTS;
    double S1t=sh.f.stot[0], S2t=sh.f.stot[1], trVt=sh.f.stot[2];
    double testStat = S1t/n;
    double varHSIC = (S2t - trVt)/n/(n-1.0);
    varHSIC = varHSIC*72.0*(n-4.0)*(n-5.0)/n/(n-1.0)/(n-2.0)/(n-3.0);
    double muX = (sK-n)/n/(n-1.0);
    double muY = (sL-n)/n/(n-1.0);
    double mHSIC = (1.0 + muX*muY - muX - muY)/n;
    double al = mHSIC*mHSIC/varHSIC;
    double bet = varHSIC*n/mHSIC;
    double p = (double)((float)(1.0-0.8));
    double lga = lgamma(al);
    double lo = 0.0, hi = al + 10.0*sqrt(al) + 100.0;
    const double zp = -0.8416212335729142957;
    double tt2 = 1.0 - 1.0/(9.0*al) + zp/(3.0*sqrt(al));
    double x = al*tt2*tt2*tt2;
    if (!(x > 0.0) || !(x < hi)) x = 0.5*hi;
    for (int it=0; it<2; ++it){
      double P = gammainc_block4(al, x, lga, tid, lane, w, sh.f.gwp, sh.f.gbs);
      double diff = P - p;
      if (diff < 0.0) lo = x; else hi = x;
      if (fabs(diff) < 1e-12) break;
      double pdf = exp(-x + (al-1.0)*log(x) - lga);
      double nx = x - diff/pdf;
      if (!(nx > lo) || !(nx < hi)) nx = 0.5*(lo+hi);
      x = nx;
    }
    if (tid==0){
      out[0]=(float)testStat;
      out[1]=(float)(bet*x);
    }
  }
}

// ===================== fallback: proven 4-dispatch chain (R7) =====================
__global__ __launch_bounds__(256) void convert_k(const float* __restrict__ X, const float* __restrict__ Y,
                                                 u16* __restrict__ Xbf, float* __restrict__ Gall,
                                                 u32* __restrict__ histsum, double* __restrict__ rowK,
                                                 double* __restrict__ rowL, double* __restrict__ sumsS,
                                                 double* __restrict__ slotbuf, u32* __restrict__ ctr){
  int t = blockIdx.x*256 + threadIdx.x;
  int rid = t >> 1, hf = t & 1;
  int z = rid >> 12, row = rid & 4095;
  const float* src = (z ? Y : X) + (size_t)row*DIM + hf*32;
  u16* basep = Xbf + ((size_t)z*32768 + (size_t)(row>>4)*128 + (row&15))*8;
  float g = 0.f;
#pragma unroll
  for (int f=0; f<4; f++){
    float4 f0 = *(const float4*)(src + f*8);
    float4 f1 = *(const float4*)(src + f*8 + 4);
    g = fmaf(f0.x,f0.x,g); g = fmaf(f0.y,f0.y,g); g = fmaf(f0.z,f0.z,g); g = fmaf(f0.w,f0.w,g);
    g = fmaf(f1.x,f1.x,g); g = fmaf(f1.y,f1.y,g); g = fmaf(f1.z,f1.z,g); g = fmaf(f1.w,f1.w,g);
    ushort4 h0, h1;
    h0.x=f2bf(f0.x); h0.y=f2bf(f0.y); h0.z=f2bf(f0.z); h0.w=f2bf(f0.w);
    h1.x=f2bf(f1.x); h1.y=f2bf(f1.y); h1.z=f2bf(f1.z); h1.w=f2bf(f1.w);
    u16* dst = basep + (size_t)(hf*4 + f)*16*8;
    *(ushort4*)dst = h0;
    *(ushort4*)(dst+4) = h1;
  }
  g += __shfl_xor(g, 1, 64);
  if (hf==0) Gall[rid] = g;
  if (t < NPTS){ rowK[t] = 0.0; rowL[t] = 0.0; }
  if (t < 2*RSTR) histsum[t] = 0u;
  if (t < 64) slotbuf[t] = 0.0;
  if (t < 16) sumsS[t] = 0.0;
  if (t == 0) *ctr = 0u;
}

__global__ __launch_bounds__(256,4) void hist_k(const u16* __restrict__ Xbf, const float* __restrict__ Gall,
                                                u32* __restrict__ histsum){
  __shared__ u32 lh[4][RSTR];
  __shared__ bf16x8 sB[1024];
  int z = blockIdx.y, tid = threadIdx.x;
  int by,bx; bmap(blockIdx.x, by, bx);
  bool isdiag = (by==bx);
  u32 wgt = isdiag ? 1u : 2u;
  int w=tid>>6, lane=tid&63, q=lane>>4, nl=lane&15;
  int cp = lane & 3;
  const bf16x8* Xb = (const bf16x8*)Xbf + (size_t)z*32768;
  const bf16x8* srcB = Xb + (size_t)(bx*8)*128;
  for (int t=tid;t<1024;t+=256) sB[t] = srcB[t];
  for (int t=tid;t<4*RSTR;t+=256) ((u32*)lh)[t]=0;
  __syncthreads();
  const float* Gz = Gall + z*NPTS;
  int ag0 = by*8 + w, ag1 = by*8 + 4 + w;
  bf16x8 a0f0 = Xb[ag0*128 + q*16 + nl];
  bf16x8 a0f1 = Xb[ag0*128 + (4+q)*16 + nl];
  bf16x8 a1f0 = Xb[ag1*128 + q*16 + nl];
  bf16x8 a1f1 = Xb[ag1*128 + (4+q)*16 + nl];
  float ga0 = Gz[ag0*16 + nl], ga1 = Gz[ag1*16 + nl];
  float g0m[4], g1m[4];
#pragma unroll
  for (int r=0;r<4;r++){ g0m[r] = __shfl(ga0, q*4+r, 64); g1m[r] = __shfl(ga1, q*4+r, 64); }
#pragma unroll
  for (int tb=0;tb<8;tb++){
    bf16x8 bf0 = sB[tb*128 + q*16 + nl];
    bf16x8 bf1 = sB[tb*128 + (4+q)*16 + nl];
    f32x4 acc0 = (f32x4)0.0f, acc1 = (f32x4)0.0f;
    acc0 = __builtin_amdgcn_mfma_f32_16x16x32_bf16(a0f0, bf0, acc0, 0,0,0);
    acc0 = __builtin_amdgcn_mfma_f32_16x16x32_bf16(a0f1, bf1, acc0, 0,0,0);
    acc1 = __builtin_amdgcn_mfma_f32_16x16x32_bf16(a1f0, bf0, acc1, 0,0,0);
    acc1 = __builtin_amdgcn_mfma_f32_16x16x32_bf16(a1f1, bf1, acc1, 0,0,0);
    int j = (bx*8 + tb)*16 + nl;
    float gb = Gz[j];
#pragma unroll
    for (int r=0;r<4;r++){
      float d0 = (g0m[r] + gb) - 2.0f*acc0[r];
      float d1 = (g1m[r] + gb) - 2.0f*acc1[r];
      if (isdiag){
        if (ag0*16 + q*4 + r == j) d0 = 0.f;
        if (ag1*16 + q*4 + r == j) d1 = 0.f;
      }
      u32 t0 = __float_as_uint(d0) >> 16;
      u32 bin0 = (t0 < WLO16) ? 0u : (t0 >= WLO16+NWBIN) ? (u32)(NWBIN+1) : (t0 - WLO16 + 1u);
      atomicAdd(&lh[cp][bin0], wgt);
      u32 t1 = __float_as_uint(d1) >> 16;
      u32 bin1 = (t1 < WLO16) ? 0u : (t1 >= WLO16+NWBIN) ? (u32)(NWBIN+1) : (t1 - WLO16 + 1u);
      atomicAdd(&lh[cp][bin1], wgt);
    }
  }
  __syncthreads();
  u32* dst = histsum + (size_t)z*RSTR;
  for (int t=tid;t<RSTR;t+=256){
    u32 v = lh[0][t] + lh[1][t] + lh[2][t] + lh[3][t];
    if (v) atomicAdd(&dst[t], v);
  }
}

__global__ __launch_bounds__(256,3) void rowsum_k(const u16* __restrict__ Xbf, const float* __restrict__ Gall,
                                                  const u32* __restrict__ histsum, float* __restrict__ scal,
                                                  double* __restrict__ rowK, double* __restrict__ rowL,
                                                  double* __restrict__ sumsS){
  __shared__ union {
    struct { u32 wsum[4]; double svals[2]; float scal_sh; } sc;
    struct { double rowacc[128]; double colLDS[4][128]; double tred[2]; } rs;
  } sh;
  __shared__ bf16x8 sB[1024];
  int z = blockIdx.y, tid = threadIdx.x;
  int w=tid>>6, lane=tid&63, q=lane>>4, nl=lane&15;
  int by,bx; bmap(blockIdx.x, by, bx);
  bool isdiag = (by==bx);
  const bf16x8* Xb = (const bf16x8*)Xbf + (size_t)z*32768;
  const bf16x8* srcB = Xb + (size_t)(bx*8)*128;
  for (int t=tid;t<1024;t+=256) sB[t] = srcB[t];
  {
    u32 c4[4] = {0,0,0,0};
    if (tid < 209){
      const u32* base = histsum + (size_t)z*RSTR + 4*tid;
      int lim = RSTR - 4*tid;
      c4[0] = base[0];
      if (lim>1) c4[1] = base[1];
      if (lim>2) c4[2] = base[2];
      if (lim>3) c4[3] = base[3];
    }
    u32 s = c4[0]+c4[1]+c4[2]+c4[3];
    u32 pre = s;
#pragma unroll
    for (int off=1; off<64; off<<=1){
      u32 t2 = __shfl_up(pre, off, 64);
      if (lane >= off) pre += t2;
    }
    if (lane==63) sh.sc.wsum[w] = pre;
    __syncthreads();
    u32 base2 = 0;
    for (int k=0;k<w;k++) base2 += sh.sc.wsum[k];
    u32 incl = base2 + pre, excl = incl - s;
    u32 ks[2] = {KF1C,KF2C};
#pragma unroll
    for (int w2=0; w2<2; w2++){
      if (ks[w2] >= excl && ks[w2] < incl){
        u32 acc = excl;
#pragma unroll
        for (int j=0;j<4;j++){
          if (ks[w2] < acc + c4[j]){
            int b = tid*4 + j;
            double lo, hi;
            if (b==0){ lo=12.0; hi=12.0; }
            else if (b>=NWBIN+1){ lo=1024.0; hi=1024.0; }
            else {
              u32 t16 = WLO16 + (u32)b - 1u;
              lo = (double)__uint_as_float(t16<<16);
              hi = (double)__uint_as_float((t16+1u)<<16);
            }
            double frac = ((double)(ks[w2]-acc) + 0.5)/(double)c4[j];
            sh.sc.svals[w2] = lo + (hi-lo)*frac;
            break;
          }
          acc += c4[j];
        }
      }
    }
    __syncthreads();
    if (tid==0){
      float med = (float)(0.5*(sh.sc.svals[0]+sh.sc.svals[1]));
      float wd = sqrtf(0.5f*med);
      float sc2 = 2.0f*wd*wd;
      sh.sc.scal_sh = sc2;
      if (blockIdx.x==0) scal[z] = sc2;
    }
    __syncthreads();
  }
  float negi = -LOG2E / sh.sc.scal_sh;
  __syncthreads();
  const float* Gz = Gall + z*NPTS;
  int ag0 = by*8 + w, ag1 = by*8 + 4 + w;
  bf16x8 a0f0 = Xb[ag0*128 + q*16 + nl];
  bf16x8 a0f1 = Xb[ag0*128 + (4+q)*16 + nl];
  bf16x8 a1f0 = Xb[ag1*128 + q*16 + nl];
  bf16x8 a1f1 = Xb[ag1*128 + (4+q)*16 + nl];
  float ga0 = Gz[ag0*16 + nl], ga1 = Gz[ag1*16 + nl];
  float g0m[4], g1m[4];
#pragma unroll
  for (int r=0;r<4;r++){ g0m[r] = __shfl(ga0, q*4+r, 64); g1m[r] = __shfl(ga1, q*4+r, 64); }
  float rs0[4] = {0,0,0,0}, rs1[4] = {0,0,0,0};
#pragma unroll
  for (int tb=0;tb<8;tb++){
    bf16x8 bf0 = sB[tb*128 + q*16 + nl];
    bf16x8 bf1 = sB[tb*128 + (4+q)*16 + nl];
    f32x4 acc0 = (f32x4)0.0f, acc1 = (f32x4)0.0f;
    acc0 = __builtin_amdgcn_mfma_f32_16x16x32_bf16(a0f0, bf0, acc0, 0,0,0);
    acc0 = __builtin_amdgcn_mfma_f32_16x16x32_bf16(a0f1, bf1, acc0, 0,0,0);
    acc1 = __builtin_amdgcn_mfma_f32_16x16x32_bf16(a1f0, bf0, acc1, 0,0,0);
    acc1 = __builtin_amdgcn_mfma_f32_16x16x32_bf16(a1f1, bf1, acc1, 0,0,0);
    int j = (bx*8 + tb)*16 + nl;
    float gb = Gz[j];
    float cs = 0.f;
#pragma unroll
    for (int r=0;r<4;r++){
      float d0 = (g0m[r] + gb) - 2.0f*acc0[r];
      float d1 = (g1m[r] + gb) - 2.0f*acc1[r];
      if (isdiag){
        if (ag0*16 + q*4 + r == j) d0 = 0.f;
        if (ag1*16 + q*4 + r == j) d1 = 0.f;
      }
      float e0 = fexp2(d0*negi);
      float e1 = fexp2(d1*negi);
      rs0[r] += e0; rs1[r] += e1;
      cs += e0 + e1;
    }
    cs += __shfl_xor(cs, 16, 64);
    cs += __shfl_xor(cs, 32, 64);
    if (q==0) sh.rs.colLDS[w][tb*16 + nl] = (double)cs;
  }
#pragma unroll
  for (int r=0;r<4;r++){
    float v0 = rs0[r], v1 = rs1[r];
    v0 += __shfl_xor(v0,1,64); v0 += __shfl_xor(v0,2,64);
    v0 += __shfl_xor(v0,4,64); v0 += __shfl_xor(v0,8,64);
    v1 += __shfl_xor(v1,1,64); v1 += __shfl_xor(v1,2,64);
    v1 += __shfl_xor(v1,4,64); v1 += __shfl_xor(v1,8,64);
    rs0[r] = v0; rs1[r] = v1;
  }
  if (nl==0){
#pragma unroll
    for (int r=0;r<4;r++){
      sh.rs.rowacc[w*16 + q*4 + r]     = (double)rs0[r];
      sh.rs.rowacc[(4+w)*16 + q*4 + r] = (double)rs1[r];
    }
  }
  __syncthreads();
  double tot = 0.0;
  if (tid < 128){
    double rv = sh.rs.rowacc[tid];
    double cv = sh.rs.colLDS[0][tid] + sh.rs.colLDS[1][tid] + sh.rs.colLDS[2][tid] + sh.rs.colLDS[3][tid];
    double* rowG = z ? rowL : rowK;
    atomicAdd(&rowG[by*128 + tid], rv);
    if (!isdiag) atomicAdd(&rowG[bx*128 + tid], cv);
    tot = rv + (isdiag ? 0.0 : cv);
  }
#pragma unroll
  for (int s2=1;s2<64;s2<<=1) tot += __shfl_xor(tot, s2, 64);
  if (lane==0 && w<2) sh.rs.tred[w] = tot;
  __syncthreads();
  if (tid==0) atomicAdd(&sumsS[z*8 + (blockIdx.x & 7)], sh.rs.tred[0] + sh.rs.tred[1]);
}

__global__ __launch_bounds__(256,3) void final_k(const u16* __restrict__ Xbf, const float* __restrict__ Gall,
                                                 const float* __restrict__ scal,
                                                 const double* __restrict__ rowK,
                                                 const double* __restrict__ rowL,
                                                 const double* __restrict__ sumsS,
                                                 double* __restrict__ slotbuf, u32* __restrict__ ctr,
                                                 float* __restrict__ out){
  __shared__ bf16x8 sBX[1024];
  __shared__ bf16x8 sBY[1024];
  __shared__ double red[4][3];
  __shared__ double gwp[4], gbs[4], stot[3];
  __shared__ int lastFlag;
  int tid = threadIdx.x;
  int b = blockIdx.x >> 1, half = blockIdx.x & 1;
  int by,bx; bmap(b,by,bx);
  bool isdiag = (by==bx);
  int w=tid>>6, lane=tid&63, q=lane>>4, nl=lane&15;
  const bf16x8* Xb = (const bf16x8*)Xbf;
  const bf16x8* Yb = Xb + 32768;
  const bf16x8* srcBX = Xb + (size_t)(bx*8)*128;
  const bf16x8* srcBY = Yb + (size_t)(bx*8)*128;
  for (int t=tid;t<1024;t+=256){ sBX[t] = srcBX[t]; sBY[t] = srcBY[t]; }
  const float* Gx = Gall;
  const float* Gy = Gall + NPTS;
  const double inv_n = 1.0/(double)NPTS;
  double sK=0.0, sL=0.0;
#pragma unroll
  for (int k2=0;k2<8;k2++){ sK += sumsS[k2]; sL += sumsS[8+k2]; }
  double tmK = sK*(inv_n*inv_n), tmL = sL*(inv_n*inv_n);
  float negx = -LOG2E/scal[0], negy = -LOG2E/scal[1];
  float S1f=0.f, S2f=0.f, trVf=0.f;
  int ag = by*8 + half*4 + w;
  bf16x8 axf0 = Xb[ag*128 + q*16 + nl];
  bf16x8 axf1 = Xb[ag*128 + (4+q)*16 + nl];
  bf16x8 ayf0 = Yb[ag*128 + q*16 + nl];
  bf16x8 ayf1 = Yb[ag*128 + (4+q)*16 + nl];
  float gaX = Gx[ag*16 + nl], gaY = Gy[ag*16 + nl];
  float gXm[4], gYm[4];
#pragma unroll
  for (int r=0;r<4;r++){ gXm[r] = __shfl(gaX, q*4+r, 64); gYm[r] = __shfl(gaY, q*4+r, 64); }
  float rmKi[4], rmLi[4];
#pragma unroll
  for (int r=0;r<4;r++){
    int i = ag*16 + q*4 + r;
    rmKi[r] = (float)(rowK[i]*inv_n); rmLi[r] = (float)(rowL[i]*inv_n);
  }
  __syncthreads();
#pragma unroll
  for (int tb=0;tb<8;tb++){
    bf16x8 bx0 = sBX[tb*128 + q*16 + nl];
    bf16x8 bx1 = sBX[tb*128 + (4+q)*16 + nl];
    bf16x8 by0 = sBY[tb*128 + q*16 + nl];
    bf16x8 by1 = sBY[tb*128 + (4+q)*16 + nl];
    f32x4 accX = (f32x4)0.0f, accY = (f32x4)0.0f;
    accX = __builtin_amdgcn_mfma_f32_16x16x32_bf16(axf0, bx0, accX, 0,0,0);
    accX = __builtin_amdgcn_mfma_f32_16x16x32_bf16(axf1, bx1, accX, 0,0,0);
    accY = __builtin_amdgcn_mfma_f32_16x16x32_bf16(ayf0, by0, accY, 0,0,0);
    accY = __builtin_amdgcn_mfma_f32_16x16x32_bf16(ayf1, by1, accY, 0,0,0);
    int j = (bx*8 + tb)*16 + nl;
    float gbX = Gx[j], gbY = Gy[j];
    float cmK = (float)(rowK[j]*inv_n - tmK);
    float cmL = (float)(rowL[j]*inv_n - tmL);
#pragma unroll
    for (int r=0;r<4;r++){
      int i = ag*16 + q*4 + r;
      float dx = (gXm[r] + gbX) - 2.0f*accX[r];
      float dy = (gYm[r] + gbY) - 2.0f*accY[r];
      bool dg = isdiag && i==j;
      if (dg){ dx = 0.f; dy = 0.f; }
      float kx = fexp2(dx*negx);
      float lv = fexp2(dy*negy);
      float kc = (kx - rmKi[r]) - cmK;
      float lc = (lv - rmLi[r]) - cmL;
      float prod = kc*lc;
      S1f += prod;
      S2f = fmaf(prod, prod, S2f);
      if (dg) trVf = fmaf(prod, prod, trVf);
    }
  }
  double S1, S2, trV;
  {
    double wgt = isdiag ? 1.0 : 2.0;
    S1 = (double)S1f * wgt;
    S2 = (double)S2f * (wgt*(1.0/36.0));
    trV = (double)trVf * (1.0/36.0);
  }
  double vals[3]={S1,S2,trV};
#pragma unroll
  for (int v=0;v<3;v++){
    double x = vals[v];
#pragma unroll
    for (int s2=1;s2<64;s2<<=1) x += __shfl_xor(x, s2, 64);
    if (lane==0) red[w][v]=x;
  }
  __syncthreads();
  if (tid < 3){
    double val = red[0][tid]+red[1][tid]+red[2][tid]+red[3][tid];
    double old = atomicAdd(&slotbuf[(size_t)(blockIdx.x & 15)*4 + tid], val);
    asm volatile("" :: "v"(old));
  }
  __syncthreads();
  if (tid==0){
    u32 old = atomicAdd(ctr, 1u);
    lastFlag = (old == (u32)(2*NBLK - 1)) ? 1 : 0;
  }
  __syncthreads();
  if (!lastFlag) return;
  if (w==0){
    double t0=0.0, t1=0.0, t2=0.0;
    if (lane < 16){
      double* sp = slotbuf + (size_t)lane*4;
      t0 = atomicAdd(&sp[0], 0.0);
      t1 = atomicAdd(&sp[1], 0.0);
      t2 = atomicAdd(&sp[2], 0.0);
    }
#pragma unroll
    for (int s2=1;s2<16;s2<<=1){
      t0 += __shfl_xor(t0, s2, 64);
      t1 += __shfl_xor(t1, s2, 64);
      t2 += __shfl_xor(t2, s2, 64);
    }
    if (lane==0){ stot[0]=t0; stot[1]=t1; stot[2]=t2; }
  }
  __syncthreads();
  const double n = (double)NPTS;
  double S1t=stot[0], S2t=stot[1], trVt=stot[2];
  double testStat = S1t/n;
  double varHSIC = (S2t - trVt)/n/(n-1.0);
  varHSIC = varHSIC*72.0*(n-4.0)*(n-5.0)/n/(n-1.0)/(n-2.0)/(n-3.0);
  double muX = (sK-n)/n/(n-1.0);
  double muY = (sL-n)/n/(n-1.0);
  double mHSIC = (1.0 + muX*muY - muX - muY)/n;
  double al = mHSIC*mHSIC/varHSIC;
  double bet = varHSIC*n/mHSIC;
  double p = (double)((float)(1.0-0.8));
  double lga = lgamma(al);
  double lo = 0.0, hi = al + 10.0*sqrt(al) + 100.0;
  const double zp = -0.8416212335729142957;
  double tt = 1.0 - 1.0/(9.0*al) + zp/(3.0*sqrt(al));
  double x = al*tt*tt*tt;
  if (!(x > 0.0) || !(x < hi)) x = 0.5*hi;
  for (int it=0; it<2; ++it){
    double P = gammainc_block4(al, x, lga, tid, lane, w, gwp, gbs);
    double diff = P - p;
    if (diff < 0.0) lo = x; else hi = x;
    if (fabs(diff) < 1e-12) break;
    double pdf = exp(-x + (al-1.0)*log(x) - lga);
    double nx = x - diff/pdf;
    if (!(nx > lo) || !(nx < hi)) nx = 0.5*(lo+hi);
    x = nx;
  }
  if (tid==0){
    out[0]=(float)testStat;
    out[1]=(float)(bet*x);
  }
}

// ---------- host ----------
extern "C" void kernel_launch(void* const* d_in, const int* in_sizes, int n_in,
                              void* d_out, int out_size, void* d_ws, size_t ws_size,
                              hipStream_t stream) {
  const float* X = (const float*)d_in[0];
  const float* Y = (const float*)d_in[1];
  float* out = (float*)d_out;
  char* ws = (char*)d_ws;

  double* sumsS    = (double*)ws;                    // 16 doubles (8 slots per z)
  float*  scal     = (float*)(ws + 128);             // 2 floats (fallback path only)
  u32*    histsum  = (u32*)(ws + 256);               // 2*836 u32 = 6688 B
  double* slotbuf  = (double*)(ws + 7168);           // 16 slots x 4 doubles = 512 B
  u32*    ctr      = (u32*)(ws + 7680);              // barrier/done counter (own cache line)
  double* rowK     = (double*)(ws + 8192);           // 32 KB
  double* rowL     = (double*)(ws + 40960);          // 32 KB
  float*  Gall     = (float*)(ws + 73728);           // 32 KB
  u16*    Xbf      = (u16*)(ws + (4u<<20));          // 1 MB (swizzled fragment-major)
  size_t need = (size_t)(4u<<20) + (size_t)2*NPTS*DIM*2;   // ~5.2 MB

  if (ws_size < need) return;

  // zero all atomic accumulators + barrier counter. The launch boundary after this
  // memset writes-back/invalidates L2s, making the zeros MALL-visible for in-kernel atomics.
  (void)hipMemsetAsync(ws, 0, 73728, stream);

  static int gridBlocks = 0;
  if (gridBlocks == 0){
    int dev = 0; (void)hipGetDevice(&dev);
    int nCU = 0; (void)hipDeviceGetAttribute(&nCU, hipDeviceAttributeMultiprocessorCount, dev);
    int maxb = 0;
    (void)hipOccupancyMaxActiveBlocksPerMultiprocessor(&maxb, reinterpret_cast<const void*>(hsic_fused), 256, 0);
    if (nCU <= 0) nCU = 256;
    if (maxb <= 0) maxb = 1;
    long g = (long)nCU * (long)maxb;
    if (g > 2*NBLK) g = 2*NBLK;
    if (g < 8) g = 8;
    gridBlocks = (int)g;
  }

  void* args[] = {(void*)&X, (void*)&Y, (void*)&Xbf, (void*)&Gall, (void*)&histsum,
                  (void*)&rowK, (void*)&rowL, (void*)&sumsS, (void*)&slotbuf,
                  (void*)&ctr, (void*)&out};
  hipError_t e = hipLaunchCooperativeKernel(reinterpret_cast<const void*>(hsic_fused),
                                            dim3(gridBlocks), dim3(256), args, 0, stream);
  if (e != hipSuccess){
    // fallback: proven 4-dispatch chain
    convert_k<<<64,256,0,stream>>>(X, Y, Xbf, Gall, histsum, rowK, rowL, sumsS, slotbuf, ctr);
    hist_k<<<dim3(NBLK,2),256,0,stream>>>(Xbf, Gall, histsum);
    rowsum_k<<<dim3(NBLK,2),256,0,stream>>>(Xbf, Gall, histsum, scal, rowK, rowL, sumsS);
    final_k<<<2*NBLK,256,0,stream>>>(Xbf, Gall, scal, rowK, rowL, sumsS, slotbuf, ctr, out);
  }
}

// Round 9
// 132.659 us; speedup vs baseline: 1.8013x; 1.8013x over previous
//
#include <hip/hip_runtime.h>

typedef unsigned int u32;
typedef unsigned short u16;
typedef __attribute__((ext_vector_type(8))) short bf16x8;   // 8 bf16 in 4 VGPRs
typedef __attribute__((ext_vector_type(4))) float f32x4;

#define NPTS 4096
#define DIM  64
#define NB   32          // 4096/128
#define NBLK 528         // NB*(NB+1)/2 upper-tri 128x128 blocks
#define WLO16 0x4140u    // window low: float bits 0x41400000 = 12.0
#define NWBIN 832        // t16 in [0x4140, 0x4480) -> D in [12, 1024)
#define RSTR 836         // histogram stride in u32 (834 bins + pad)
#define LOG2E 1.4426950408889634f
// full-matrix ranks: diag(4096 zeros) + doubled upper-tri; m_ut = 8386560
#define KF1C 8390654u
#define KF2C 8390656u

// Swizzled fragment-major layout (chunk = bf16x8 = 16 B):
//   chunk_index(row, f) = (row>>4)*128 + f*16 + (row&15)

// map linear upper-tri block id -> (by,bx), bx>=by
__device__ __forceinline__ void bmap(int b, int& by, int& bx){
  by = 0;
  while (b >= NB - by){ b -= NB - by; by++; }
  bx = by + b;
}

// fp32 -> bf16 bits, round-nearest-even
__device__ __forceinline__ u16 f2bf(float x){
  u32 u = __float_as_uint(x);
  return (u16)((u + 0x7fffu + ((u>>16)&1u)) >> 16);
}

// bare v_exp_f32 (args bounded in [-5,0]: no range/denorm handling needed)
__device__ __forceinline__ float fexp2(float x){
  return __builtin_amdgcn_exp2f(x);
}

// ---------- dispatch 1: convert to swizzled bf16 + norms; zero accumulators ----------
// 128 blocks (4 threads/row, 16 floats each): R6's 64-block grid touched only 1/4 of CUs.
__global__ __launch_bounds__(256) void convert_k(const float* __restrict__ X, const float* __restrict__ Y,
                                                 u16* __restrict__ Xbf, float* __restrict__ Gall,
                                                 u32* __restrict__ histsum, double* __restrict__ rowK,
                                                 double* __restrict__ rowL, double* __restrict__ sumsS,
                                                 double* __restrict__ slotbuf, u32* __restrict__ ctr){
  int t = blockIdx.x*256 + threadIdx.x;     // 32768 threads, 4 per row (quarter-row each)
  int rid = t >> 2, qtr = t & 3;
  int z = rid >> 12, row = rid & 4095;
  const float* src = (z ? Y : X) + (size_t)row*DIM + qtr*16;
  u16* basep = Xbf + ((size_t)z*32768 + (size_t)(row>>4)*128 + (row&15))*8;
  float g = 0.f;
#pragma unroll
  for (int f2=0; f2<2; f2++){               // global fragment f = qtr*2 + f2 (8 elems each)
    float4 f0 = *(const float4*)(src + f2*8);
    float4 f1 = *(const float4*)(src + f2*8 + 4);
    g = fmaf(f0.x,f0.x,g); g = fmaf(f0.y,f0.y,g); g = fmaf(f0.z,f0.z,g); g = fmaf(f0.w,f0.w,g);
    g = fmaf(f1.x,f1.x,g); g = fmaf(f1.y,f1.y,g); g = fmaf(f1.z,f1.z,g); g = fmaf(f1.w,f1.w,g);
    ushort4 h0, h1;
    h0.x=f2bf(f0.x); h0.y=f2bf(f0.y); h0.z=f2bf(f0.z); h0.w=f2bf(f0.w);
    h1.x=f2bf(f1.x); h1.y=f2bf(f1.y); h1.z=f2bf(f1.z); h1.w=f2bf(f1.w);
    u16* dst = basep + (size_t)(qtr*2 + f2)*16*8;
    *(ushort4*)dst = h0;
    *(ushort4*)(dst+4) = h1;
  }
  // combine the 4 quarter-row partial norms (quarters sit in 4 consecutive lanes)
  g += __shfl_xor(g, 1, 64);
  g += __shfl_xor(g, 2, 64);
  if (qtr==0) Gall[rid] = g;
  // zero atomic accumulators (workspace is re-poisoned between runs)
  if (t < NPTS){ rowK[t] = 0.0; rowL[t] = 0.0; }
  if (t < 2*RSTR) histsum[t] = 0u;
  if (t < 64) slotbuf[t] = 0.0;
  if (t < 16) sumsS[t] = 0.0;
  if (t == 0) *ctr = 0u;
}

// ---------- dispatch 2: upper-tri block histogram, LDS-staged B panel ----------
__global__ __launch_bounds__(256,4) void hist_k(const u16* __restrict__ Xbf, const float* __restrict__ Gall,
                                                u32* __restrict__ histsum){
  __shared__ u32 lh[4][RSTR];
  __shared__ bf16x8 sB[1024];               // 16 KB: B panel (8 row-groups x 128 chunks)
  int z = blockIdx.y, tid = threadIdx.x;
  int by,bx; bmap(blockIdx.x, by, bx);
  bool isdiag = (by==bx);
  u32 wgt = isdiag ? 1u : 2u;
  int w=tid>>6, lane=tid&63, q=lane>>4, nl=lane&15;
  int cp = lane & 3;                        // replica copy: splits same-bin serialization 4x
  const bf16x8* Xb = (const bf16x8*)Xbf + (size_t)z*32768;
  const bf16x8* srcB = Xb + (size_t)(bx*8)*128;
  for (int t=tid;t<1024;t+=256) sB[t] = srcB[t];
  for (int t=tid;t<4*RSTR;t+=256) ((u32*)lh)[t]=0;
  __syncthreads();
  const float* Gz = Gall + z*NPTS;
  int ag0 = by*8 + w, ag1 = by*8 + 4 + w;
  bf16x8 a0f0 = Xb[ag0*128 + q*16 + nl];
  bf16x8 a0f1 = Xb[ag0*128 + (4+q)*16 + nl];
  bf16x8 a1f0 = Xb[ag1*128 + q*16 + nl];
  bf16x8 a1f1 = Xb[ag1*128 + (4+q)*16 + nl];
  float ga0 = Gz[ag0*16 + nl], ga1 = Gz[ag1*16 + nl];
  float g0m[4], g1m[4];
#pragma unroll
  for (int r=0;r<4;r++){ g0m[r] = __shfl(ga0, q*4+r, 64); g1m[r] = __shfl(ga1, q*4+r, 64); }
#pragma unroll
  for (int tb=0;tb<8;tb++){
    bf16x8 bf0 = sB[tb*128 + q*16 + nl];
    bf16x8 bf1 = sB[tb*128 + (4+q)*16 + nl];
    f32x4 acc0 = (f32x4)0.0f, acc1 = (f32x4)0.0f;
    acc0 = __builtin_amdgcn_mfma_f32_16x16x32_bf16(a0f0, bf0, acc0, 0,0,0);
    acc0 = __builtin_amdgcn_mfma_f32_16x16x32_bf16(a0f1, bf1, acc0, 0,0,0);
    acc1 = __builtin_amdgcn_mfma_f32_16x16x32_bf16(a1f0, bf0, acc1, 0,0,0);
    acc1 = __builtin_amdgcn_mfma_f32_16x16x32_bf16(a1f1, bf1, acc1, 0,0,0);
    int j = (bx*8 + tb)*16 + nl;
    float gb = Gz[j];
#pragma unroll
    for (int r=0;r<4;r++){
      float d0 = (g0m[r] + gb) - 2.0f*acc0[r];
      float d1 = (g1m[r] + gb) - 2.0f*acc1[r];
      if (isdiag){
        if (ag0*16 + q*4 + r == j) d0 = 0.f;
        if (ag1*16 + q*4 + r == j) d1 = 0.f;
      }
      u32 t0 = __float_as_uint(d0) >> 16;
      u32 bin0 = (t0 < WLO16) ? 0u : (t0 >= WLO16+NWBIN) ? (u32)(NWBIN+1) : (t0 - WLO16 + 1u);
      atomicAdd(&lh[cp][bin0], wgt);
      u32 t1 = __float_as_uint(d1) >> 16;
      u32 bin1 = (t1 < WLO16) ? 0u : (t1 >= WLO16+NWBIN) ? (u32)(NWBIN+1) : (t1 - WLO16 + 1u);
      atomicAdd(&lh[cp][bin1], wgt);
    }
  }
  __syncthreads();
  u32* dst = histsum + (size_t)z*RSTR;
  for (int t=tid;t<RSTR;t+=256){
    u32 v = lh[0][t] + lh[1][t] + lh[2][t] + lh[3][t];
    if (v) atomicAdd(&dst[t], v);
  }
}

// ---------- dispatch 3: per-block median scan + upper-tri row sums (LDS-staged B) ----------
// f32 inner math (reference is f32); f64 only at cross-thread reduction.
__global__ __launch_bounds__(256,3) void rowsum_k(const u16* __restrict__ Xbf, const float* __restrict__ Gall,
                                                  const u32* __restrict__ histsum, float* __restrict__ scal,
                                                  double* __restrict__ rowK, double* __restrict__ rowL,
                                                  double* __restrict__ sumsS){
  __shared__ union {
    struct { u32 wsum[4]; double svals[2]; float scal_sh; } sc;
    struct { double rowacc[128]; double colLDS[4][128]; double tred[2]; } rs;
  } sh;
  __shared__ bf16x8 sB[1024];               // 16 KB B panel
  int z = blockIdx.y, tid = threadIdx.x;
  int w=tid>>6, lane=tid&63, q=lane>>4, nl=lane&15;
  int by,bx; bmap(blockIdx.x, by, bx);
  bool isdiag = (by==bx);
  const bf16x8* Xb = (const bf16x8*)Xbf + (size_t)z*32768;
  const bf16x8* srcB = Xb + (size_t)(bx*8)*128;
  for (int t=tid;t<1024;t+=256) sB[t] = srcB[t];   // staging overlaps the scan prologue

  // --- scan prologue: compute median width from histsum (every block, L2 hits) ---
  {
    u32 c4[4] = {0,0,0,0};
    if (tid < 209){
      const u32* base = histsum + (size_t)z*RSTR + 4*tid;
      int lim = RSTR - 4*tid;
      c4[0] = base[0];
      if (lim>1) c4[1] = base[1];
      if (lim>2) c4[2] = base[2];
      if (lim>3) c4[3] = base[3];
    }
    u32 s = c4[0]+c4[1]+c4[2]+c4[3];
    u32 pre = s;
#pragma unroll
    for (int off=1; off<64; off<<=1){
      u32 t2 = __shfl_up(pre, off, 64);
      if (lane >= off) pre += t2;
    }
    if (lane==63) sh.sc.wsum[w] = pre;
    __syncthreads();
    u32 base2 = 0;
    for (int k=0;k<w;k++) base2 += sh.sc.wsum[k];
    u32 incl = base2 + pre, excl = incl - s;
    u32 ks[2] = {KF1C,KF2C};
#pragma unroll
    for (int w2=0; w2<2; w2++){
      if (ks[w2] >= excl && ks[w2] < incl){
        u32 acc = excl;
#pragma unroll
        for (int j=0;j<4;j++){
          if (ks[w2] < acc + c4[j]){
            int b = tid*4 + j;
            double lo, hi;
            if (b==0){ lo=12.0; hi=12.0; }
            else if (b>=NWBIN+1){ lo=1024.0; hi=1024.0; }
            else {
              u32 t16 = WLO16 + (u32)b - 1u;
              lo = (double)__uint_as_float(t16<<16);
              hi = (double)__uint_as_float((t16+1u)<<16);
            }
            double frac = ((double)(ks[w2]-acc) + 0.5)/(double)c4[j];
            sh.sc.svals[w2] = lo + (hi-lo)*frac;
            break;
          }
          acc += c4[j];
        }
      }
    }
    __syncthreads();
    if (tid==0){
      float med = (float)(0.5*(sh.sc.svals[0]+sh.sc.svals[1]));
      float wd = sqrtf(0.5f*med);
      float sc2 = 2.0f*wd*wd;
      sh.sc.scal_sh = sc2;
      if (blockIdx.x==0) scal[z] = sc2;    // for final_k
    }
    __syncthreads();
  }
  float negi = -LOG2E / sh.sc.scal_sh;      // exp(x) = exp2(x*log2e): fold into scale
  __syncthreads();                          // done reading union.sc before union.rs writes

  // --- rowsum body ---
  const float* Gz = Gall + z*NPTS;
  int ag0 = by*8 + w, ag1 = by*8 + 4 + w;
  bf16x8 a0f0 = Xb[ag0*128 + q*16 + nl];
  bf16x8 a0f1 = Xb[ag0*128 + (4+q)*16 + nl];
  bf16x8 a1f0 = Xb[ag1*128 + q*16 + nl];
  bf16x8 a1f1 = Xb[ag1*128 + (4+q)*16 + nl];
  float ga0 = Gz[ag0*16 + nl], ga1 = Gz[ag1*16 + nl];
  float g0m[4], g1m[4];
#pragma unroll
  for (int r=0;r<4;r++){ g0m[r] = __shfl(ga0, q*4+r, 64); g1m[r] = __shfl(ga1, q*4+r, 64); }
  float rs0[4] = {0,0,0,0}, rs1[4] = {0,0,0,0};
#pragma unroll
  for (int tb=0;tb<8;tb++){
    bf16x8 bf0 = sB[tb*128 + q*16 + nl];
    bf16x8 bf1 = sB[tb*128 + (4+q)*16 + nl];
    f32x4 acc0 = (f32x4)0.0f, acc1 = (f32x4)0.0f;
    acc0 = __builtin_amdgcn_mfma_f32_16x16x32_bf16(a0f0, bf0, acc0, 0,0,0);
    acc0 = __builtin_amdgcn_mfma_f32_16x16x32_bf16(a0f1, bf1, acc0, 0,0,0);
    acc1 = __builtin_amdgcn_mfma_f32_16x16x32_bf16(a1f0, bf0, acc1, 0,0,0);
    acc1 = __builtin_amdgcn_mfma_f32_16x16x32_bf16(a1f1, bf1, acc1, 0,0,0);
    int j = (bx*8 + tb)*16 + nl;
    float gb = Gz[j];
    float cs = 0.f;
#pragma unroll
    for (int r=0;r<4;r++){
      float d0 = (g0m[r] + gb) - 2.0f*acc0[r];
      float d1 = (g1m[r] + gb) - 2.0f*acc1[r];
      if (isdiag){
        if (ag0*16 + q*4 + r == j) d0 = 0.f;    // exact K_ii = 1
        if (ag1*16 + q*4 + r == j) d1 = 0.f;
      }
      float e0 = fexp2(d0*negi);
      float e1 = fexp2(d1*negi);
      rs0[r] += e0; rs1[r] += e1;
      cs += e0 + e1;
    }
    cs += __shfl_xor(cs, 16, 64);
    cs += __shfl_xor(cs, 32, 64);
    if (q==0) sh.rs.colLDS[w][tb*16 + nl] = (double)cs;
  }
#pragma unroll
  for (int r=0;r<4;r++){
    float v0 = rs0[r], v1 = rs1[r];
    v0 += __shfl_xor(v0,1,64); v0 += __shfl_xor(v0,2,64);
    v0 += __shfl_xor(v0,4,64); v0 += __shfl_xor(v0,8,64);
    v1 += __shfl_xor(v1,1,64); v1 += __shfl_xor(v1,2,64);
    v1 += __shfl_xor(v1,4,64); v1 += __shfl_xor(v1,8,64);
    rs0[r] = v0; rs1[r] = v1;
  }
  if (nl==0){
#pragma unroll
    for (int r=0;r<4;r++){
      sh.rs.rowacc[w*16 + q*4 + r]     = (double)rs0[r];
      sh.rs.rowacc[(4+w)*16 + q*4 + r] = (double)rs1[r];
    }
  }
  __syncthreads();
  double tot = 0.0;
  if (tid < 128){
    double rv = sh.rs.rowacc[tid];
    double cv = sh.rs.colLDS[0][tid] + sh.rs.colLDS[1][tid] + sh.rs.colLDS[2][tid] + sh.rs.colLDS[3][tid];
    double* rowG = z ? rowL : rowK;
    atomicAdd(&rowG[by*128 + tid], rv);
    if (!isdiag) atomicAdd(&rowG[bx*128 + tid], cv);
    tot = rv + (isdiag ? 0.0 : cv);
  }
#pragma unroll
  for (int s2=1;s2<64;s2<<=1) tot += __shfl_xor(tot, s2, 64);
  if (lane==0 && w<2) sh.rs.tred[w] = tot;
  __syncthreads();
  if (tid==0) atomicAdd(&sumsS[z*8 + (blockIdx.x & 7)], sh.rs.tred[0] + sh.rs.tred[1]);
}

// ---------- block-parallel gamma series: 1024 terms/batch (4 per thread) ----------
// termination loosened 1e-17 -> 1e-13: residual tail < 1e-13 of total, far below f32 output needs
__device__ double gammainc_block4(double a, double x, double lga,
                                  int tid, int lane, int w,
                                  double* wp /*shared[4]*/, double* bs /*shared[4]*/){
  double C = 1.0/a;
  double psum = 0.0;
  for (int b=0;b<512;b++){
    double k0 = (double)(b*1024 + tid*4);
    double r1 = x/(a+k0+1.0), r2 = x/(a+k0+2.0), r3 = x/(a+k0+3.0), r4 = x/(a+k0+4.0);
    double p12 = r1*r2;
    double pl = p12*(r3*r4);              // product of this thread's 4 ratios
    double pp = pl;                        // inclusive prefix across 64 lanes
#pragma unroll
    for (int s=1;s<64;s<<=1){
      double t = __shfl_up(pp, s, 64);
      if (lane >= s) pp *= t;
    }
    if (lane==63) wp[w] = pp;
    __syncthreads();
    double cross = 1.0;
    for (int k2=0;k2<w;k2++) cross *= wp[k2];
    double call = wp[0]*wp[1]*wp[2]*wp[3];
    double excl = __shfl_up(pp, 1, 64);
    if (lane==0) excl = 1.0;
    double base = C*cross*excl;            // prefix before this thread's 4 terms
    double t1 = base*r1, t2 = base*p12, t3 = t2*r3, t4 = base*pl;
    psum += (t1+t2)+(t3+t4);
    double Cn = C*call;
    C = Cn;
    double rlast = x/(a + (double)(b*1024 + 1024));
    __syncthreads();                       // wp reused next iteration
    if (rlast < 1.0 && Cn*rlast/(1.0-rlast) < 1e-13) break;
  }
#pragma unroll
  for (int s=1;s<64;s<<=1) psum += __shfl_xor(psum, s, 64);
  if (lane==0) bs[w] = psum;
  __syncthreads();
  double total = 1.0/a + bs[0]+bs[1]+bs[2]+bs[3];
  __syncthreads();
  return exp(-x + a*log(x) - lga) * total;
}

// ---------- dispatch 4: centered products (1056 half-tile blocks, LDS panels) + tail finalize ----------
// (256,3): cap 170 >= natural ~100-128 -> no spill; LDS 33 KB allows 4 blocks/CU.
__global__ __launch_bounds__(256,3) void final_k(const u16* __restrict__ Xbf, const float* __restrict__ Gall,
                                                 const float* __restrict__ scal,
                                                 const double* __restrict__ rowK,
                                                 const double* __restrict__ rowL,
                                                 const double* __restrict__ sumsS,
                                                 double* __restrict__ slotbuf, u32* __restrict__ ctr,
                                                 float* __restrict__ out){
  __shared__ bf16x8 sBX[1024];              // 16 KB: X B-panel
  __shared__ bf16x8 sBY[1024];              // 16 KB: Y B-panel
  __shared__ double red[4][3];
  __shared__ double gwp[4], gbs[4], stot[3];
  __shared__ int lastFlag;
  int tid = threadIdx.x;
  int b = blockIdx.x >> 1, half = blockIdx.x & 1;
  int by,bx; bmap(b,by,bx);
  bool isdiag = (by==bx);
  int w=tid>>6, lane=tid&63, q=lane>>4, nl=lane&15;
  const bf16x8* Xb = (const bf16x8*)Xbf;
  const bf16x8* Yb = Xb + 32768;
  const bf16x8* srcBX = Xb + (size_t)(bx*8)*128;
  const bf16x8* srcBY = Yb + (size_t)(bx*8)*128;
  for (int t=tid;t<1024;t+=256){ sBX[t] = srcBX[t]; sBY[t] = srcBY[t]; }
  const float* Gx = Gall;
  const float* Gy = Gall + NPTS;
  const double inv_n = 1.0/(double)NPTS;
  double sK=0.0, sL=0.0;
#pragma unroll
  for (int k2=0;k2<8;k2++){ sK += sumsS[k2]; sL += sumsS[8+k2]; }
  double tmK = sK*(inv_n*inv_n), tmL = sL*(inv_n*inv_n);
  float negx = -LOG2E/scal[0], negy = -LOG2E/scal[1];   // exp2-folded
  float S1f=0.f, S2f=0.f, trVf=0.f;        // f32 per-thread partials (<=32 terms)
  int ag = by*8 + half*4 + w;              // this block's 4 A row-groups
  bf16x8 axf0 = Xb[ag*128 + q*16 + nl];
  bf16x8 axf1 = Xb[ag*128 + (4+q)*16 + nl];
  bf16x8 ayf0 = Yb[ag*128 + q*16 + nl];
  bf16x8 ayf1 = Yb[ag*128 + (4+q)*16 + nl];
  float gaX = Gx[ag*16 + nl], gaY = Gy[ag*16 + nl];
  float gXm[4], gYm[4];
#pragma unroll
  for (int r=0;r<4;r++){ gXm[r] = __shfl(gaX, q*4+r, 64); gYm[r] = __shfl(gaY, q*4+r, 64); }
  float rmKi[4], rmLi[4];
#pragma unroll
  for (int r=0;r<4;r++){
    int i = ag*16 + q*4 + r;
    rmKi[r] = (float)(rowK[i]*inv_n); rmLi[r] = (float)(rowL[i]*inv_n);
  }
  __syncthreads();                          // panels staged
#pragma unroll
  for (int tb=0;tb<8;tb++){
    bf16x8 bx0 = sBX[tb*128 + q*16 + nl];
    bf16x8 bx1 = sBX[tb*128 + (4+q)*16 + nl];
    bf16x8 by0 = sBY[tb*128 + q*16 + nl];
    bf16x8 by1 = sBY[tb*128 + (4+q)*16 + nl];
    f32x4 accX = (f32x4)0.0f, accY = (f32x4)0.0f;
    accX = __builtin_amdgcn_mfma_f32_16x16x32_bf16(axf0, bx0, accX, 0,0,0);
    accX = __builtin_amdgcn_mfma_f32_16x16x32_bf16(axf1, bx1, accX, 0,0,0);
    accY = __builtin_amdgcn_mfma_f32_16x16x32_bf16(ayf0, by0, accY, 0,0,0);
    accY = __builtin_amdgcn_mfma_f32_16x16x32_bf16(ayf1, by1, accY, 0,0,0);
    int j = (bx*8 + tb)*16 + nl;
    float gbX = Gx[j], gbY = Gy[j];
    float cmK = (float)(rowK[j]*inv_n - tmK);   // f64 difference (cancellation-safe), then f32
    float cmL = (float)(rowL[j]*inv_n - tmL);
#pragma unroll
    for (int r=0;r<4;r++){
      int i = ag*16 + q*4 + r;
      float dx = (gXm[r] + gbX) - 2.0f*accX[r];
      float dy = (gYm[r] + gbY) - 2.0f*accY[r];
      bool dg = isdiag && i==j;
      if (dg){ dx = 0.f; dy = 0.f; }
      float kx = fexp2(dx*negx);
      float lv = fexp2(dy*negy);
      float kc = (kx - rmKi[r]) - cmK;
      float lc = (lv - rmLi[r]) - cmL;
      float prod = kc*lc;
      S1f += prod;
      S2f = fmaf(prod, prod, S2f);
      if (dg) trVf = fmaf(prod, prod, trVf);
    }
  }
  double S1, S2, trV;
  {
    double wgt = isdiag ? 1.0 : 2.0;
    S1 = (double)S1f * wgt;
    S2 = (double)S2f * (wgt*(1.0/36.0));
    trV = (double)trVf * (1.0/36.0);
  }
  double vals[3]={S1,S2,trV};
#pragma unroll
  for (int v=0;v<3;v++){
    double x = vals[v];
#pragma unroll
    for (int s2=1;s2<64;s2<<=1) x += __shfl_xor(x, s2, 64);
    if (lane==0) red[w][v]=x;
  }
  __syncthreads();
  if (tid < 3){
    double val = red[0][tid]+red[1][tid]+red[2][tid]+red[3][tid];
    // returning atomic: completion (not just issue) before the barrier's vmcnt drain
    double old = atomicAdd(&slotbuf[(size_t)(blockIdx.x & 15)*4 + tid], val);
    asm volatile("" :: "v"(old));          // keep the return value live
  }
  __syncthreads();                          // drains vmcnt: slot adds complete before ctr bump
  if (tid==0){
    u32 old = atomicAdd(ctr, 1u);
    lastFlag = (old == (u32)(2*NBLK - 1)) ? 1 : 0;
  }
  __syncthreads();
  if (!lastFlag) return;

  // ---- tail block (all 256 threads): reduce slots + gamma-ppf ----
  if (w==0){
    double t0=0.0, t1=0.0, t2=0.0;
    if (lane < 16){
      double* sp = slotbuf + (size_t)lane*4;
      t0 = atomicAdd(&sp[0], 0.0);   // atomic RMW read: coherent across XCD L2s
      t1 = atomicAdd(&sp[1], 0.0);
      t2 = atomicAdd(&sp[2], 0.0);
    }
#pragma unroll
    for (int s2=1;s2<16;s2<<=1){
      t0 += __shfl_xor(t0, s2, 64);
      t1 += __shfl_xor(t1, s2, 64);
      t2 += __shfl_xor(t2, s2, 64);
    }
    if (lane==0){ stot[0]=t0; stot[1]=t1; stot[2]=t2; }
  }
  __syncthreads();
  const double n = (double)NPTS;
  double S1t=stot[0], S2t=stot[1], trVt=stot[2];
  double testStat = S1t/n;
  double varHSIC = (S2t - trVt)/n/(n-1.0);
  varHSIC = varHSIC*72.0*(n-4.0)*(n-5.0)/n/(n-1.0)/(n-2.0)/(n-3.0);
  double muX = (sK-n)/n/(n-1.0);   // trace(K) = n exactly (diag forced to 1)
  double muY = (sL-n)/n/(n-1.0);
  double mHSIC = (1.0 + muX*muY - muX - muY)/n;
  double al = mHSIC*mHSIC/varHSIC;
  double bet = varHSIC*n/mHSIC;
  double p = (double)((float)(1.0-0.8));
  double lga = lgamma(al);
  double lo = 0.0, hi = al + 10.0*sqrt(al) + 100.0;
  const double zp = -0.8416212335729142957;  // Phi^-1(0.2)
  double tt = 1.0 - 1.0/(9.0*al) + zp/(3.0*sqrt(al));
  double x = al*tt*tt*tt;
  if (!(x > 0.0) || !(x < hi)) x = 0.5*hi;
  for (int it=0; it<2; ++it){
    double P = gammainc_block4(al, x, lga, tid, lane, w, gwp, gbs);
    double diff = P - p;
    if (diff < 0.0) lo = x; else hi = x;
    if (fabs(diff) < 1e-12) break;
    double pdf = exp(-x + (al-1.0)*log(x) - lga);
    double nx = x - diff/pdf;
    if (!(nx > lo) || !(nx < hi)) nx = 0.5*(lo+hi);
    x = nx;
  }
  if (tid==0){
    out[0]=(float)testStat;
    out[1]=(float)(bet*x);
  }
}

// ---------- host ----------
extern "C" void kernel_launch(void* const* d_in, const int* in_sizes, int n_in,
                              void* d_out, int out_size, void* d_ws, size_t ws_size,
                              hipStream_t stream) {
  const float* X = (const float*)d_in[0];
  const float* Y = (const float*)d_in[1];
  float* out = (float*)d_out;
  char* ws = (char*)d_ws;

  double* sumsS    = (double*)ws;                    // 16 doubles (8 slots per z)
  float*  scal     = (float*)(ws + 128);             // 2 floats
  u32*    histsum  = (u32*)(ws + 256);               // 2*836 u32 = 6688 B
  double* slotbuf  = (double*)(ws + 7168);           // 16 slots x 4 doubles = 512 B
  u32*    ctr      = (u32*)(ws + 7680);              // done counter
  double* rowK     = (double*)(ws + 8192);           // 32 KB
  double* rowL     = (double*)(ws + 40960);          // 32 KB
  float*  Gall     = (float*)(ws + 73728);           // 32 KB
  u16*    Xbf      = (u16*)(ws + (4u<<20));          // 1 MB (swizzled fragment-major)
  size_t need = (size_t)(4u<<20) + (size_t)2*NPTS*DIM*2;   // ~5.2 MB

  if (ws_size < need) return;

  convert_k<<<128,256,0,stream>>>(X, Y, Xbf, Gall, histsum, rowK, rowL, sumsS, slotbuf, ctr);
  hist_k<<<dim3(NBLK,2),256,0,stream>>>(Xbf, Gall, histsum);
  rowsum_k<<<dim3(NBLK,2),256,0,stream>>>(Xbf, Gall, histsum, scal, rowK, rowL, sumsS);
  final_k<<<2*NBLK,256,0,stream>>>(Xbf, Gall, scal, rowK, rowL, sumsS, slotbuf, ctr, out);
}

// Round 10
// 128.910 us; speedup vs baseline: 1.8537x; 1.0291x over previous
//
#include <hip/hip_runtime.h>

typedef unsigned int u32;
typedef unsigned short u16;
typedef __attribute__((ext_vector_type(8))) short bf16x8;   // 8 bf16 in 4 VGPRs
typedef __attribute__((ext_vector_type(4))) float f32x4;

#define NPTS 4096
#define DIM  64
#define NB   32          // 4096/128
#define NBLK 528         // NB*(NB+1)/2 upper-tri 128x128 blocks
#define WLO16 0x4140u    // window low: float bits 0x41400000 = 12.0
#define NWBIN 832        // t16 in [0x4140, 0x4480) -> D in [12, 1024)
#define RSTR 836         // histogram stride in u32 (834 bins + pad)
#define LOG2E 1.4426950408889634f
// full-matrix ranks: diag(4096 zeros) + doubled upper-tri; m_ut = 8386560
#define KF1C 8390654u
#define KF2C 8390656u

// Swizzled fragment-major layout (chunk = bf16x8 = 16 B):
//   chunk_index(row, f) = (row>>4)*128 + f*16 + (row&15)

// map linear upper-tri block id -> (by,bx), bx>=by
__device__ __forceinline__ void bmap(int b, int& by, int& bx){
  by = 0;
  while (b >= NB - by){ b -= NB - by; by++; }
  bx = by + b;
}

// fp32 -> bf16 bits, round-nearest-even
__device__ __forceinline__ u16 f2bf(float x){
  u32 u = __float_as_uint(x);
  return (u16)((u + 0x7fffu + ((u>>16)&1u)) >> 16);
}

// bare v_exp_f32 (args bounded in [-5,0]: no range/denorm handling needed)
__device__ __forceinline__ float fexp2(float x){
  return __builtin_amdgcn_exp2f(x);
}

// ---------- dispatch 1: convert to swizzled bf16 + norms; zero accumulators ----------
__global__ __launch_bounds__(256) void convert_k(const float* __restrict__ X, const float* __restrict__ Y,
                                                 u16* __restrict__ Xbf, float* __restrict__ Gall,
                                                 u32* __restrict__ histsum, double* __restrict__ rowK,
                                                 double* __restrict__ rowL, double* __restrict__ sumsS,
                                                 double* __restrict__ slotbuf, u32* __restrict__ ctr){
  int t = blockIdx.x*256 + threadIdx.x;     // 32768 threads, 4 per row (quarter-row each)
  int rid = t >> 2, qtr = t & 3;
  int z = rid >> 12, row = rid & 4095;
  const float* src = (z ? Y : X) + (size_t)row*DIM + qtr*16;
  u16* basep = Xbf + ((size_t)z*32768 + (size_t)(row>>4)*128 + (row&15))*8;
  float g = 0.f;
#pragma unroll
  for (int f2=0; f2<2; f2++){               // global fragment f = qtr*2 + f2 (8 elems each)
    float4 f0 = *(const float4*)(src + f2*8);
    float4 f1 = *(const float4*)(src + f2*8 + 4);
    g = fmaf(f0.x,f0.x,g); g = fmaf(f0.y,f0.y,g); g = fmaf(f0.z,f0.z,g); g = fmaf(f0.w,f0.w,g);
    g = fmaf(f1.x,f1.x,g); g = fmaf(f1.y,f1.y,g); g = fmaf(f1.z,f1.z,g); g = fmaf(f1.w,f1.w,g);
    ushort4 h0, h1;
    h0.x=f2bf(f0.x); h0.y=f2bf(f0.y); h0.z=f2bf(f0.z); h0.w=f2bf(f0.w);
    h1.x=f2bf(f1.x); h1.y=f2bf(f1.y); h1.z=f2bf(f1.z); h1.w=f2bf(f1.w);
    u16* dst = basep + (size_t)(qtr*2 + f2)*16*8;
    *(ushort4*)dst = h0;
    *(ushort4*)(dst+4) = h1;
  }
  // combine the 4 quarter-row partial norms (quarters sit in 4 consecutive lanes)
  g += __shfl_xor(g, 1, 64);
  g += __shfl_xor(g, 2, 64);
  if (qtr==0) Gall[rid] = g;
  // zero atomic accumulators (workspace is re-poisoned between runs)
  if (t < NPTS){ rowK[t] = 0.0; rowL[t] = 0.0; }
  if (t < 2*RSTR) histsum[t] = 0u;
  if (t < 64) slotbuf[t] = 0.0;
  if (t < 16) sumsS[t] = 0.0;
  if (t == 0) *ctr = 0u;
}

// ---------- dispatch 2: upper-tri block histogram, LDS-staged B panel + B-side G ----------
__global__ __launch_bounds__(256,4) void hist_k(const u16* __restrict__ Xbf, const float* __restrict__ Gall,
                                                u32* __restrict__ histsum){
  __shared__ u32 lh[4][RSTR];
  __shared__ bf16x8 sB[1024];               // 16 KB: B panel (8 row-groups x 128 chunks)
  __shared__ float sG[128];                 // B panel norms
  int z = blockIdx.y, tid = threadIdx.x;
  int by,bx; bmap(blockIdx.x, by, bx);
  bool isdiag = (by==bx);
  u32 wgt = isdiag ? 1u : 2u;
  int w=tid>>6, lane=tid&63, q=lane>>4, nl=lane&15;
  int cp = lane & 3;                        // replica copy: splits same-bin serialization 4x
  const bf16x8* Xb = (const bf16x8*)Xbf + (size_t)z*32768;
  const float* Gz = Gall + z*NPTS;
  const bf16x8* srcB = Xb + (size_t)(bx*8)*128;
  for (int t=tid;t<1024;t+=256) sB[t] = srcB[t];
  if (tid < 128) sG[tid] = Gz[bx*128 + tid];
  for (int t=tid;t<4*RSTR;t+=256) ((u32*)lh)[t]=0;
  __syncthreads();
  int ag0 = by*8 + w, ag1 = by*8 + 4 + w;
  bf16x8 a0f0 = Xb[ag0*128 + q*16 + nl];
  bf16x8 a0f1 = Xb[ag0*128 + (4+q)*16 + nl];
  bf16x8 a1f0 = Xb[ag1*128 + q*16 + nl];
  bf16x8 a1f1 = Xb[ag1*128 + (4+q)*16 + nl];
  float ga0 = Gz[ag0*16 + nl], ga1 = Gz[ag1*16 + nl];
  float g0m[4], g1m[4];
#pragma unroll
  for (int r=0;r<4;r++){ g0m[r] = __shfl(ga0, q*4+r, 64); g1m[r] = __shfl(ga1, q*4+r, 64); }
#pragma unroll
  for (int tb=0;tb<8;tb++){
    bf16x8 bf0 = sB[tb*128 + q*16 + nl];
    bf16x8 bf1 = sB[tb*128 + (4+q)*16 + nl];
    f32x4 acc0 = (f32x4)0.0f, acc1 = (f32x4)0.0f;
    acc0 = __builtin_amdgcn_mfma_f32_16x16x32_bf16(a0f0, bf0, acc0, 0,0,0);
    acc0 = __builtin_amdgcn_mfma_f32_16x16x32_bf16(a0f1, bf1, acc0, 0,0,0);
    acc1 = __builtin_amdgcn_mfma_f32_16x16x32_bf16(a1f0, bf0, acc1, 0,0,0);
    acc1 = __builtin_amdgcn_mfma_f32_16x16x32_bf16(a1f1, bf1, acc1, 0,0,0);
    int j = (bx*8 + tb)*16 + nl;
    float gb = sG[tb*16 + nl];
#pragma unroll
    for (int r=0;r<4;r++){
      float d0 = (g0m[r] + gb) - 2.0f*acc0[r];
      float d1 = (g1m[r] + gb) - 2.0f*acc1[r];
      if (isdiag){
        if (ag0*16 + q*4 + r == j) d0 = 0.f;
        if (ag1*16 + q*4 + r == j) d1 = 0.f;
      }
      u32 t0 = __float_as_uint(d0) >> 16;
      u32 bin0 = (t0 < WLO16) ? 0u : (t0 >= WLO16+NWBIN) ? (u32)(NWBIN+1) : (t0 - WLO16 + 1u);
      atomicAdd(&lh[cp][bin0], wgt);
      u32 t1 = __float_as_uint(d1) >> 16;
      u32 bin1 = (t1 < WLO16) ? 0u : (t1 >= WLO16+NWBIN) ? (u32)(NWBIN+1) : (t1 - WLO16 + 1u);
      atomicAdd(&lh[cp][bin1], wgt);
    }
  }
  __syncthreads();
  u32* dst = histsum + (size_t)z*RSTR;
  for (int t=tid;t<RSTR;t+=256){
    u32 v = lh[0][t] + lh[1][t] + lh[2][t] + lh[3][t];
    if (v) atomicAdd(&dst[t], v);
  }
}

// ---------- dispatch 3: per-block median scan + upper-tri row sums (LDS-staged B + G) ----------
// f32 inner math; (256,4): f32 body fits 128 VGPR (R5: the (256,4) spill was f64 final_k, not rowsum)
__global__ __launch_bounds__(256,4) void rowsum_k(const u16* __restrict__ Xbf, const float* __restrict__ Gall,
                                                  const u32* __restrict__ histsum, float* __restrict__ scal,
                                                  double* __restrict__ rowK, double* __restrict__ rowL,
                                                  double* __restrict__ sumsS){
  __shared__ union {
    struct { u32 wsum[4]; double svals[2]; float scal_sh; } sc;
    struct { double rowacc[128]; double colLDS[4][128]; double tred[2]; } rs;
  } sh;
  __shared__ bf16x8 sB[1024];               // 16 KB B panel
  __shared__ float sG[128];                 // B panel norms
  int z = blockIdx.y, tid = threadIdx.x;
  int w=tid>>6, lane=tid&63, q=lane>>4, nl=lane&15;
  int by,bx; bmap(blockIdx.x, by, bx);
  bool isdiag = (by==bx);
  const bf16x8* Xb = (const bf16x8*)Xbf + (size_t)z*32768;
  const float* Gz = Gall + z*NPTS;
  const bf16x8* srcB = Xb + (size_t)(bx*8)*128;
  for (int t=tid;t<1024;t+=256) sB[t] = srcB[t];   // staging overlaps the scan prologue
  if (tid < 128) sG[tid] = Gz[bx*128 + tid];

  // --- scan prologue: compute median width from histsum (every block, L2 hits) ---
  {
    u32 c4[4] = {0,0,0,0};
    if (tid < 209){
      const u32* base = histsum + (size_t)z*RSTR + 4*tid;
      int lim = RSTR - 4*tid;
      c4[0] = base[0];
      if (lim>1) c4[1] = base[1];
      if (lim>2) c4[2] = base[2];
      if (lim>3) c4[3] = base[3];
    }
    u32 s = c4[0]+c4[1]+c4[2]+c4[3];
    u32 pre = s;
#pragma unroll
    for (int off=1; off<64; off<<=1){
      u32 t2 = __shfl_up(pre, off, 64);
      if (lane >= off) pre += t2;
    }
    if (lane==63) sh.sc.wsum[w] = pre;
    __syncthreads();
    u32 base2 = 0;
    for (int k=0;k<w;k++) base2 += sh.sc.wsum[k];
    u32 incl = base2 + pre, excl = incl - s;
    u32 ks[2] = {KF1C,KF2C};
#pragma unroll
    for (int w2=0; w2<2; w2++){
      if (ks[w2] >= excl && ks[w2] < incl){
        u32 acc = excl;
#pragma unroll
        for (int j=0;j<4;j++){
          if (ks[w2] < acc + c4[j]){
            int b = tid*4 + j;
            double lo, hi;
            if (b==0){ lo=12.0; hi=12.0; }
            else if (b>=NWBIN+1){ lo=1024.0; hi=1024.0; }
            else {
              u32 t16 = WLO16 + (u32)b - 1u;
              lo = (double)__uint_as_float(t16<<16);
              hi = (double)__uint_as_float((t16+1u)<<16);
            }
            double frac = ((double)(ks[w2]-acc) + 0.5)/(double)c4[j];
            sh.sc.svals[w2] = lo + (hi-lo)*frac;
            break;
          }
          acc += c4[j];
        }
      }
    }
    __syncthreads();
    if (tid==0){
      float med = (float)(0.5*(sh.sc.svals[0]+sh.sc.svals[1]));
      float wd = sqrtf(0.5f*med);
      float sc2 = 2.0f*wd*wd;
      sh.sc.scal_sh = sc2;
      if (blockIdx.x==0) scal[z] = sc2;    // for final_k
    }
    __syncthreads();
  }
  float negi = -LOG2E / sh.sc.scal_sh;      // exp(x) = exp2(x*log2e): fold into scale
  __syncthreads();                          // done reading union.sc before union.rs writes

  // --- rowsum body ---
  int ag0 = by*8 + w, ag1 = by*8 + 4 + w;
  bf16x8 a0f0 = Xb[ag0*128 + q*16 + nl];
  bf16x8 a0f1 = Xb[ag0*128 + (4+q)*16 + nl];
  bf16x8 a1f0 = Xb[ag1*128 + q*16 + nl];
  bf16x8 a1f1 = Xb[ag1*128 + (4+q)*16 + nl];
  float ga0 = Gz[ag0*16 + nl], ga1 = Gz[ag1*16 + nl];
  float g0m[4], g1m[4];
#pragma unroll
  for (int r=0;r<4;r++){ g0m[r] = __shfl(ga0, q*4+r, 64); g1m[r] = __shfl(ga1, q*4+r, 64); }
  float rs0[4] = {0,0,0,0}, rs1[4] = {0,0,0,0};
#pragma unroll
  for (int tb=0;tb<8;tb++){
    bf16x8 bf0 = sB[tb*128 + q*16 + nl];
    bf16x8 bf1 = sB[tb*128 + (4+q)*16 + nl];
    f32x4 acc0 = (f32x4)0.0f, acc1 = (f32x4)0.0f;
    acc0 = __builtin_amdgcn_mfma_f32_16x16x32_bf16(a0f0, bf0, acc0, 0,0,0);
    acc0 = __builtin_amdgcn_mfma_f32_16x16x32_bf16(a0f1, bf1, acc0, 0,0,0);
    acc1 = __builtin_amdgcn_mfma_f32_16x16x32_bf16(a1f0, bf0, acc1, 0,0,0);
    acc1 = __builtin_amdgcn_mfma_f32_16x16x32_bf16(a1f1, bf1, acc1, 0,0,0);
    int j = (bx*8 + tb)*16 + nl;
    float gb = sG[tb*16 + nl];
    float cs = 0.f;
#pragma unroll
    for (int r=0;r<4;r++){
      float d0 = (g0m[r] + gb) - 2.0f*acc0[r];
      float d1 = (g1m[r] + gb) - 2.0f*acc1[r];
      if (isdiag){
        if (ag0*16 + q*4 + r == j) d0 = 0.f;    // exact K_ii = 1
        if (ag1*16 + q*4 + r == j) d1 = 0.f;
      }
      float e0 = fexp2(d0*negi);
      float e1 = fexp2(d1*negi);
      rs0[r] += e0; rs1[r] += e1;
      cs += e0 + e1;
    }
    cs += __shfl_xor(cs, 16, 64);
    cs += __shfl_xor(cs, 32, 64);
    if (q==0) sh.rs.colLDS[w][tb*16 + nl] = (double)cs;
  }
#pragma unroll
  for (int r=0;r<4;r++){
    float v0 = rs0[r], v1 = rs1[r];
    v0 += __shfl_xor(v0,1,64); v0 += __shfl_xor(v0,2,64);
    v0 += __shfl_xor(v0,4,64); v0 += __shfl_xor(v0,8,64);
    v1 += __shfl_xor(v1,1,64); v1 += __shfl_xor(v1,2,64);
    v1 += __shfl_xor(v1,4,64); v1 += __shfl_xor(v1,8,64);
    rs0[r] = v0; rs1[r] = v1;
  }
  if (nl==0){
#pragma unroll
    for (int r=0;r<4;r++){
      sh.rs.rowacc[w*16 + q*4 + r]     = (double)rs0[r];
      sh.rs.rowacc[(4+w)*16 + q*4 + r] = (double)rs1[r];
    }
  }
  __syncthreads();
  double tot = 0.0;
  if (tid < 128){
    double rv = sh.rs.rowacc[tid];
    double cv = sh.rs.colLDS[0][tid] + sh.rs.colLDS[1][tid] + sh.rs.colLDS[2][tid] + sh.rs.colLDS[3][tid];
    double* rowG = z ? rowL : rowK;
    atomicAdd(&rowG[by*128 + tid], rv);
    if (!isdiag) atomicAdd(&rowG[bx*128 + tid], cv);
    tot = rv + (isdiag ? 0.0 : cv);
  }
#pragma unroll
  for (int s2=1;s2<64;s2<<=1) tot += __shfl_xor(tot, s2, 64);
  if (lane==0 && w<2) sh.rs.tred[w] = tot;
  __syncthreads();
  if (tid==0) atomicAdd(&sumsS[z*8 + (blockIdx.x & 7)], sh.rs.tred[0] + sh.rs.tred[1]);
}

// ---------- block-parallel gamma series: 2048 terms/batch (8 per thread) ----------
// termination 1e-13: residual tail far below f32 output needs
__device__ double gammainc_block8(double a, double x, double lga,
                                  int tid, int lane, int w,
                                  double* wp /*shared[4]*/, double* bs /*shared[4]*/){
  double C = 1.0/a;
  double psum = 0.0;
  for (int b=0;b<256;b++){
    double k0 = (double)(b*2048 + tid*8);
    double r1 = x/(a+k0+1.0), r2 = x/(a+k0+2.0), r3 = x/(a+k0+3.0), r4 = x/(a+k0+4.0);
    double r5 = x/(a+k0+5.0), r6 = x/(a+k0+6.0), r7 = x/(a+k0+7.0), r8 = x/(a+k0+8.0);
    double p12 = r1*r2, p34 = r3*r4, p56 = r5*r6, p78 = r7*r8;
    double p14 = p12*p34, p58 = p56*p78;
    double pl = p14*p58;                   // product of this thread's 8 ratios
    double pp = pl;                        // inclusive prefix across 64 lanes
#pragma unroll
    for (int s=1;s<64;s<<=1){
      double t = __shfl_up(pp, s, 64);
      if (lane >= s) pp *= t;
    }
    if (lane==63) wp[w] = pp;
    __syncthreads();
    double cross = 1.0;
    for (int k2=0;k2<w;k2++) cross *= wp[k2];
    double call = wp[0]*wp[1]*wp[2]*wp[3];
    double excl = __shfl_up(pp, 1, 64);
    if (lane==0) excl = 1.0;
    double base = C*cross*excl;            // prefix before this thread's 8 terms
    double t1 = base*r1, t2 = base*p12, t3 = t2*r3, t4 = base*p14;
    double t5 = t4*r5, t6 = t4*p56, t7 = t6*r7, t8 = base*pl;
    psum += ((t1+t2)+(t3+t4)) + ((t5+t6)+(t7+t8));
    double Cn = C*call;
    C = Cn;
    double rlast = x/(a + (double)(b*2048 + 2048));
    __syncthreads();                       // wp reused next iteration
    if (rlast < 1.0 && Cn*rlast/(1.0-rlast) < 1e-13) break;
  }
#pragma unroll
  for (int s=1;s<64;s<<=1) psum += __shfl_xor(psum, s, 64);
  if (lane==0) bs[w] = psum;
  __syncthreads();
  double total = 1.0/a + bs[0]+bs[1]+bs[2]+bs[3];
  __syncthreads();
  return exp(-x + a*log(x) - lga) * total;
}

// ---------- dispatch 4: centered products (1056 half-tile blocks) + tail finalize ----------
// (256,3): cap 170 >= natural ~100-128 -> no spill; LDS ~35 KB allows 4 blocks/CU.
// B-side G and column means staged to LDS as f32: no f64 and no global loads in the main loop.
__global__ __launch_bounds__(256,3) void final_k(const u16* __restrict__ Xbf, const float* __restrict__ Gall,
                                                 const float* __restrict__ scal,
                                                 const double* __restrict__ rowK,
                                                 const double* __restrict__ rowL,
                                                 const double* __restrict__ sumsS,
                                                 double* __restrict__ slotbuf, u32* __restrict__ ctr,
                                                 float* __restrict__ out){
  __shared__ bf16x8 sBX[1024];              // 16 KB: X B-panel
  __shared__ bf16x8 sBY[1024];              // 16 KB: Y B-panel
  __shared__ float sGX[128], sGY[128];      // B-panel norms
  __shared__ float scmK[128], scmL[128];    // centered col means (f32, precomputed once)
  __shared__ double red[4][3];
  __shared__ double gwp[4], gbs[4], stot[3];
  __shared__ int lastFlag;
  int tid = threadIdx.x;
  int b = blockIdx.x >> 1, half = blockIdx.x & 1;
  int by,bx; bmap(b,by,bx);
  bool isdiag = (by==bx);
  int w=tid>>6, lane=tid&63, q=lane>>4, nl=lane&15;
  const bf16x8* Xb = (const bf16x8*)Xbf;
  const bf16x8* Yb = Xb + 32768;
  const bf16x8* srcBX = Xb + (size_t)(bx*8)*128;
  const bf16x8* srcBY = Yb + (size_t)(bx*8)*128;
  for (int t=tid;t<1024;t+=256){ sBX[t] = srcBX[t]; sBY[t] = srcBY[t]; }
  const float* Gx = Gall;
  const float* Gy = Gall + NPTS;
  const double inv_n = 1.0/(double)NPTS;
  double sK=0.0, sL=0.0;
#pragma unroll
  for (int k2=0;k2<8;k2++){ sK += sumsS[k2]; sL += sumsS[8+k2]; }
  double tmK = sK*(inv_n*inv_n), tmL = sL*(inv_n*inv_n);
  if (tid < 128){
    int j = bx*128 + tid;
    sGX[tid] = Gx[j];
    sGY[tid] = Gy[j];
    scmK[tid] = (float)(rowK[j]*inv_n - tmK);   // f64 difference (cancellation-safe), then f32
    scmL[tid] = (float)(rowL[j]*inv_n - tmL);
  }
  float negx = -LOG2E/scal[0], negy = -LOG2E/scal[1];   // exp2-folded
  float S1f=0.f, S2f=0.f, trVf=0.f;        // f32 per-thread partials (<=32 terms)
  int ag = by*8 + half*4 + w;              // this block's 4 A row-groups
  bf16x8 axf0 = Xb[ag*128 + q*16 + nl];
  bf16x8 axf1 = Xb[ag*128 + (4+q)*16 + nl];
  bf16x8 ayf0 = Yb[ag*128 + q*16 + nl];
  bf16x8 ayf1 = Yb[ag*128 + (4+q)*16 + nl];
  float gaX = Gx[ag*16 + nl], gaY = Gy[ag*16 + nl];
  float gXm[4], gYm[4];
#pragma unroll
  for (int r=0;r<4;r++){ gXm[r] = __shfl(gaX, q*4+r, 64); gYm[r] = __shfl(gaY, q*4+r, 64); }
  float rmKi[4], rmLi[4];
#pragma unroll
  for (int r=0;r<4;r++){
    int i = ag*16 + q*4 + r;
    rmKi[r] = (float)(rowK[i]*inv_n); rmLi[r] = (float)(rowL[i]*inv_n);
  }
  __syncthreads();                          // panels + G/cm staged
#pragma unroll
  for (int tb=0;tb<8;tb++){
    bf16x8 bx0 = sBX[tb*128 + q*16 + nl];
    bf16x8 bx1 = sBX[tb*128 + (4+q)*16 + nl];
    bf16x8 by0 = sBY[tb*128 + q*16 + nl];
    bf16x8 by1 = sBY[tb*128 + (4+q)*16 + nl];
    f32x4 accX = (f32x4)0.0f, accY = (f32x4)0.0f;
    accX = __builtin_amdgcn_mfma_f32_16x16x32_bf16(axf0, bx0, accX, 0,0,0);
    accX = __builtin_amdgcn_mfma_f32_16x16x32_bf16(axf1, bx1, accX, 0,0,0);
    accY = __builtin_amdgcn_mfma_f32_16x16x32_bf16(ayf0, by0, accY, 0,0,0);
    accY = __builtin_amdgcn_mfma_f32_16x16x32_bf16(ayf1, by1, accY, 0,0,0);
    int jj = tb*16 + nl;
    int j = bx*128 + jj;
    float gbX = sGX[jj], gbY = sGY[jj];
    float cmK = scmK[jj], cmL = scmL[jj];
#pragma unroll
    for (int r=0;r<4;r++){
      int i = ag*16 + q*4 + r;
      float dx = (gXm[r] + gbX) - 2.0f*accX[r];
      float dy = (gYm[r] + gbY) - 2.0f*accY[r];
      bool dg = isdiag && i==j;
      if (dg){ dx = 0.f; dy = 0.f; }
      float kx = fexp2(dx*negx);
      float lv = fexp2(dy*negy);
      float kc = (kx - rmKi[r]) - cmK;
      float lc = (lv - rmLi[r]) - cmL;
      float prod = kc*lc;
      S1f += prod;
      S2f = fmaf(prod, prod, S2f);
      if (dg) trVf = fmaf(prod, prod, trVf);
    }
  }
  double S1, S2, trV;
  {
    double wgt = isdiag ? 1.0 : 2.0;
    S1 = (double)S1f * wgt;
    S2 = (double)S2f * (wgt*(1.0/36.0));
    trV = (double)trVf * (1.0/36.0);
  }
  double vals[3]={S1,S2,trV};
#pragma unroll
  for (int v=0;v<3;v++){
    double x = vals[v];
#pragma unroll
    for (int s2=1;s2<64;s2<<=1) x += __shfl_xor(x, s2, 64);
    if (lane==0) red[w][v]=x;
  }
  __syncthreads();
  if (tid < 3){
    double val = red[0][tid]+red[1][tid]+red[2][tid]+red[3][tid];
    // returning atomic: completion (not just issue) before the barrier's vmcnt drain
    double old = atomicAdd(&slotbuf[(size_t)(blockIdx.x & 15)*4 + tid], val);
    asm volatile("" :: "v"(old));          // keep the return value live
  }
  __syncthreads();                          // drains vmcnt: slot adds complete before ctr bump
  if (tid==0){
    u32 old = atomicAdd(ctr, 1u);
    lastFlag = (old == (u32)(2*NBLK - 1)) ? 1 : 0;
  }
  __syncthreads();
  if (!lastFlag) return;

  // ---- tail block (all 256 threads): reduce slots + gamma-ppf ----
  if (w==0){
    double t0=0.0, t1=0.0, t2=0.0;
    if (lane < 16){
      double* sp = slotbuf + (size_t)lane*4;
      t0 = atomicAdd(&sp[0], 0.0);   // atomic RMW read: coherent across XCD L2s
      t1 = atomicAdd(&sp[1], 0.0);
      t2 = atomicAdd(&sp[2], 0.0);
    }
#pragma unroll
    for (int s2=1;s2<16;s2<<=1){
      t0 += __shfl_xor(t0, s2, 64);
      t1 += __shfl_xor(t1, s2, 64);
      t2 += __shfl_xor(t2, s2, 64);
    }
    if (lane==0){ stot[0]=t0; stot[1]=t1; stot[2]=t2; }
  }
  __syncthreads();
  const double n = (double)NPTS;
  double S1t=stot[0], S2t=stot[1], trVt=stot[2];
  double testStat = S1t/n;
  double varHSIC = (S2t - trVt)/n/(n-1.0);
  varHSIC = varHSIC*72.0*(n-4.0)*(n-5.0)/n/(n-1.0)/(n-2.0)/(n-3.0);
  double muX = (sK-n)/n/(n-1.0);   // trace(K) = n exactly (diag forced to 1)
  double muY = (sL-n)/n/(n-1.0);
  double mHSIC = (1.0 + muX*muY - muX - muY)/n;
  double al = mHSIC*mHSIC/varHSIC;
  double bet = varHSIC*n/mHSIC;
  double p = (double)((float)(1.0-0.8));
  double lga = lgamma(al);
  double lo = 0.0, hi = al + 10.0*sqrt(al) + 100.0;
  const double zp = -0.8416212335729142957;  // Phi^-1(0.2)
  double tt = 1.0 - 1.0/(9.0*al) + zp/(3.0*sqrt(al));
  double x = al*tt*tt*tt;
  if (!(x > 0.0) || !(x < hi)) x = 0.5*hi;
  for (int it=0; it<2; ++it){
    double P = gammainc_block8(al, x, lga, tid, lane, w, gwp, gbs);
    double diff = P - p;
    if (diff < 0.0) lo = x; else hi = x;
    if (fabs(diff) < 1e-12) break;
    double pdf = exp(-x + (al-1.0)*log(x) - lga);
    double nx = x - diff/pdf;
    if (!(nx > lo) || !(nx < hi)) nx = 0.5*(lo+hi);
    x = nx;
  }
  if (tid==0){
    out[0]=(float)testStat;
    out[1]=(float)(bet*x);
  }
}

// ---------- host ----------
extern "C" void kernel_launch(void* const* d_in, const int* in_sizes, int n_in,
                              void* d_out, int out_size, void* d_ws, size_t ws_size,
                              hipStream_t stream) {
  const float* X = (const float*)d_in[0];
  const float* Y = (const float*)d_in[1];
  float* out = (float*)d_out;
  char* ws = (char*)d_ws;

  double* sumsS    = (double*)ws;                    // 16 doubles (8 slots per z)
  float*  scal     = (float*)(ws + 128);             // 2 floats
  u32*    histsum  = (u32*)(ws + 256);               // 2*836 u32 = 6688 B
  double* slotbuf  = (double*)(ws + 7168);           // 16 slots x 4 doubles = 512 B
  u32*    ctr      = (u32*)(ws + 7680);              // done counter
  double* rowK     = (double*)(ws + 8192);           // 32 KB
  double* rowL     = (double*)(ws + 40960);          // 32 KB
  float*  Gall     = (float*)(ws + 73728);           // 32 KB
  u16*    Xbf      = (u16*)(ws + (4u<<20));          // 1 MB (swizzled fragment-major)
  size_t need = (size_t)(4u<<20) + (size_t)2*NPTS*DIM*2;   // ~5.2 MB

  if (ws_size < need) return;

  convert_k<<<128,256,0,stream>>>(X, Y, Xbf, Gall, histsum, rowK, rowL, sumsS, slotbuf, ctr);
  hist_k<<<dim3(NBLK,2),256,0,stream>>>(Xbf, Gall, histsum);
  rowsum_k<<<dim3(NBLK,2),256,0,stream>>>(Xbf, Gall, histsum, scal, rowK, rowL, sumsS);
  final_k<<<2*NBLK,256,0,stream>>>(Xbf, Gall, scal, rowK, rowL, sumsS, slotbuf, ctr, out);
}

// Round 11
// 128.705 us; speedup vs baseline: 1.8566x; 1.0016x over previous
//
#include <hip/hip_runtime.h>

typedef unsigned int u32;
typedef unsigned short u16;
typedef __attribute__((ext_vector_type(8))) short bf16x8;   // 8 bf16 in 4 VGPRs
typedef __attribute__((ext_vector_type(4))) float f32x4;

#define NPTS 4096
#define DIM  64
#define NB   32          // 4096/128
#define NBLK 528         // NB*(NB+1)/2 upper-tri 128x128 blocks
#define WLO16 0x4140u    // window low: float bits 0x41400000 = 12.0
#define NWBIN 832        // t16 in [0x4140, 0x4480) -> D in [12, 1024)
#define RSTR 836         // histogram stride in u32 (834 bins + pad)
#define LOG2E 1.4426950408889634f
// full-matrix ranks: diag(4096 zeros) + doubled upper-tri; m_ut = 8386560
#define KF1C 8390654u
#define KF2C 8390656u

// Swizzled fragment-major layout (chunk = bf16x8 = 16 B):
//   chunk_index(row, f) = (row>>4)*128 + f*16 + (row&15)

// map linear upper-tri block id -> (by,bx), bx>=by
__device__ __forceinline__ void bmap(int b, int& by, int& bx){
  by = 0;
  while (b >= NB - by){ b -= NB - by; by++; }
  bx = by + b;
}

// fp32 -> bf16 bits, round-nearest-even
__device__ __forceinline__ u16 f2bf(float x){
  u32 u = __float_as_uint(x);
  return (u16)((u + 0x7fffu + ((u>>16)&1u)) >> 16);
}

// bare v_exp_f32 (args bounded in [-5,0]: no range/denorm handling needed)
__device__ __forceinline__ float fexp2(float x){
  return __builtin_amdgcn_exp2f(x);
}

// ---------- dispatch 1: convert to swizzled bf16 + norms; zero accumulators ----------
__global__ __launch_bounds__(256) void convert_k(const float* __restrict__ X, const float* __restrict__ Y,
                                                 u16* __restrict__ Xbf, float* __restrict__ Gall,
                                                 u32* __restrict__ histsum, double* __restrict__ rowK,
                                                 double* __restrict__ rowL, double* __restrict__ sumsS,
                                                 double* __restrict__ slotbuf, u32* __restrict__ ctr){
  int t = blockIdx.x*256 + threadIdx.x;     // 32768 threads, 4 per row (quarter-row each)
  int rid = t >> 2, qtr = t & 3;
  int z = rid >> 12, row = rid & 4095;
  const float* src = (z ? Y : X) + (size_t)row*DIM + qtr*16;
  u16* basep = Xbf + ((size_t)z*32768 + (size_t)(row>>4)*128 + (row&15))*8;
  float g = 0.f;
#pragma unroll
  for (int f2=0; f2<2; f2++){               // global fragment f = qtr*2 + f2 (8 elems each)
    float4 f0 = *(const float4*)(src + f2*8);
    float4 f1 = *(const float4*)(src + f2*8 + 4);
    g = fmaf(f0.x,f0.x,g); g = fmaf(f0.y,f0.y,g); g = fmaf(f0.z,f0.z,g); g = fmaf(f0.w,f0.w,g);
    g = fmaf(f1.x,f1.x,g); g = fmaf(f1.y,f1.y,g); g = fmaf(f1.z,f1.z,g); g = fmaf(f1.w,f1.w,g);
    ushort4 h0, h1;
    h0.x=f2bf(f0.x); h0.y=f2bf(f0.y); h0.z=f2bf(f0.z); h0.w=f2bf(f0.w);
    h1.x=f2bf(f1.x); h1.y=f2bf(f1.y); h1.z=f2bf(f1.z); h1.w=f2bf(f1.w);
    u16* dst = basep + (size_t)(qtr*2 + f2)*16*8;
    *(ushort4*)dst = h0;
    *(ushort4*)(dst+4) = h1;
  }
  // combine the 4 quarter-row partial norms (quarters sit in 4 consecutive lanes)
  g += __shfl_xor(g, 1, 64);
  g += __shfl_xor(g, 2, 64);
  if (qtr==0) Gall[rid] = g;
  // zero atomic accumulators (workspace is re-poisoned between runs)
  if (t < NPTS){ rowK[t] = 0.0; rowL[t] = 0.0; }
  if (t < 2*RSTR) histsum[t] = 0u;
  if (t < 64) slotbuf[t] = 0.0;
  if (t < 16) sumsS[t] = 0.0;
  if (t == 0) *ctr = 0u;
}

// ---------- dispatch 2: upper-tri block histogram, LDS-staged B panel + B-side G ----------
__global__ __launch_bounds__(256,4) void hist_k(const u16* __restrict__ Xbf, const float* __restrict__ Gall,
                                                u32* __restrict__ histsum){
  __shared__ u32 lh[4][RSTR];
  __shared__ bf16x8 sB[1024];               // 16 KB: B panel (8 row-groups x 128 chunks)
  __shared__ float sG[128];                 // B panel norms
  int z = blockIdx.y, tid = threadIdx.x;
  int by,bx; bmap(blockIdx.x, by, bx);
  bool isdiag = (by==bx);
  u32 wgt = isdiag ? 1u : 2u;
  int w=tid>>6, lane=tid&63, q=lane>>4, nl=lane&15;
  int cp = lane & 3;                        // replica copy: splits same-bin serialization 4x
  const bf16x8* Xb = (const bf16x8*)Xbf + (size_t)z*32768;
  const float* Gz = Gall + z*NPTS;
  const bf16x8* srcB = Xb + (size_t)(bx*8)*128;
  for (int t=tid;t<1024;t+=256) sB[t] = srcB[t];
  if (tid < 128) sG[tid] = Gz[bx*128 + tid];
  for (int t=tid;t<4*RSTR;t+=256) ((u32*)lh)[t]=0;
  __syncthreads();
  int ag0 = by*8 + w, ag1 = by*8 + 4 + w;
  bf16x8 a0f0 = Xb[ag0*128 + q*16 + nl];
  bf16x8 a0f1 = Xb[ag0*128 + (4+q)*16 + nl];
  bf16x8 a1f0 = Xb[ag1*128 + q*16 + nl];
  bf16x8 a1f1 = Xb[ag1*128 + (4+q)*16 + nl];
  float ga0 = Gz[ag0*16 + nl], ga1 = Gz[ag1*16 + nl];
  float g0m[4], g1m[4];
#pragma unroll
  for (int r=0;r<4;r++){ g0m[r] = __shfl(ga0, q*4+r, 64); g1m[r] = __shfl(ga1, q*4+r, 64); }
#pragma unroll
  for (int tb=0;tb<8;tb++){
    bf16x8 bf0 = sB[tb*128 + q*16 + nl];
    bf16x8 bf1 = sB[tb*128 + (4+q)*16 + nl];
    f32x4 acc0 = (f32x4)0.0f, acc1 = (f32x4)0.0f;
    acc0 = __builtin_amdgcn_mfma_f32_16x16x32_bf16(a0f0, bf0, acc0, 0,0,0);
    acc0 = __builtin_amdgcn_mfma_f32_16x16x32_bf16(a0f1, bf1, acc0, 0,0,0);
    acc1 = __builtin_amdgcn_mfma_f32_16x16x32_bf16(a1f0, bf0, acc1, 0,0,0);
    acc1 = __builtin_amdgcn_mfma_f32_16x16x32_bf16(a1f1, bf1, acc1, 0,0,0);
    int j = (bx*8 + tb)*16 + nl;
    float gb = sG[tb*16 + nl];
#pragma unroll
    for (int r=0;r<4;r++){
      float d0 = (g0m[r] + gb) - 2.0f*acc0[r];
      float d1 = (g1m[r] + gb) - 2.0f*acc1[r];
      if (isdiag){
        if (ag0*16 + q*4 + r == j) d0 = 0.f;
        if (ag1*16 + q*4 + r == j) d1 = 0.f;
      }
      u32 t0 = __float_as_uint(d0) >> 16;
      u32 bin0 = (t0 < WLO16) ? 0u : (t0 >= WLO16+NWBIN) ? (u32)(NWBIN+1) : (t0 - WLO16 + 1u);
      atomicAdd(&lh[cp][bin0], wgt);
      u32 t1 = __float_as_uint(d1) >> 16;
      u32 bin1 = (t1 < WLO16) ? 0u : (t1 >= WLO16+NWBIN) ? (u32)(NWBIN+1) : (t1 - WLO16 + 1u);
      atomicAdd(&lh[cp][bin1], wgt);
    }
  }
  __syncthreads();
  u32* dst = histsum + (size_t)z*RSTR;
  for (int t=tid;t<RSTR;t+=256){
    u32 v = lh[0][t] + lh[1][t] + lh[2][t] + lh[3][t];
    if (v) atomicAdd(&dst[t], v);
  }
}

// ---------- dispatch 3: per-block median scan + upper-tri row sums (LDS-staged B + G) ----------
// f32 inner math; (256,4): f32 body fits 128 VGPR (R10 verified: passed, gained)
__global__ __launch_bounds__(256,4) void rowsum_k(const u16* __restrict__ Xbf, const float* __restrict__ Gall,
                                                  const u32* __restrict__ histsum, float* __restrict__ scal,
                                                  double* __restrict__ rowK, double* __restrict__ rowL,
                                                  double* __restrict__ sumsS){
  __shared__ union {
    struct { u32 wsum[4]; double svals[2]; float scal_sh; } sc;
    struct { double rowacc[128]; double colLDS[4][128]; double tred[2]; } rs;
  } sh;
  __shared__ bf16x8 sB[1024];               // 16 KB B panel
  __shared__ float sG[128];                 // B panel norms
  int z = blockIdx.y, tid = threadIdx.x;
  int w=tid>>6, lane=tid&63, q=lane>>4, nl=lane&15;
  int by,bx; bmap(blockIdx.x, by, bx);
  bool isdiag = (by==bx);
  const bf16x8* Xb = (const bf16x8*)Xbf + (size_t)z*32768;
  const float* Gz = Gall + z*NPTS;
  const bf16x8* srcB = Xb + (size_t)(bx*8)*128;
  for (int t=tid;t<1024;t+=256) sB[t] = srcB[t];   // staging overlaps the scan prologue
  if (tid < 128) sG[tid] = Gz[bx*128 + tid];

  // --- scan prologue: compute median width from histsum (every block, L2 hits) ---
  {
    u32 c4[4] = {0,0,0,0};
    if (tid < 209){
      const u32* base = histsum + (size_t)z*RSTR + 4*tid;
      int lim = RSTR - 4*tid;
      c4[0] = base[0];
      if (lim>1) c4[1] = base[1];
      if (lim>2) c4[2] = base[2];
      if (lim>3) c4[3] = base[3];
    }
    u32 s = c4[0]+c4[1]+c4[2]+c4[3];
    u32 pre = s;
#pragma unroll
    for (int off=1; off<64; off<<=1){
      u32 t2 = __shfl_up(pre, off, 64);
      if (lane >= off) pre += t2;
    }
    if (lane==63) sh.sc.wsum[w] = pre;
    __syncthreads();
    u32 base2 = 0;
    for (int k=0;k<w;k++) base2 += sh.sc.wsum[k];
    u32 incl = base2 + pre, excl = incl - s;
    u32 ks[2] = {KF1C,KF2C};
#pragma unroll
    for (int w2=0; w2<2; w2++){
      if (ks[w2] >= excl && ks[w2] < incl){
        u32 acc = excl;
#pragma unroll
        for (int j=0;j<4;j++){
          if (ks[w2] < acc + c4[j]){
            int b = tid*4 + j;
            double lo, hi;
            if (b==0){ lo=12.0; hi=12.0; }
            else if (b>=NWBIN+1){ lo=1024.0; hi=1024.0; }
            else {
              u32 t16 = WLO16 + (u32)b - 1u;
              lo = (double)__uint_as_float(t16<<16);
              hi = (double)__uint_as_float((t16+1u)<<16);
            }
            double frac = ((double)(ks[w2]-acc) + 0.5)/(double)c4[j];
            sh.sc.svals[w2] = lo + (hi-lo)*frac;
            break;
          }
          acc += c4[j];
        }
      }
    }
    __syncthreads();
    if (tid==0){
      float med = (float)(0.5*(sh.sc.svals[0]+sh.sc.svals[1]));
      float wd = sqrtf(0.5f*med);
      float sc2 = 2.0f*wd*wd;
      sh.sc.scal_sh = sc2;
      if (blockIdx.x==0) scal[z] = sc2;    // for final_k
    }
    __syncthreads();
  }
  float negi = -LOG2E / sh.sc.scal_sh;      // exp(x) = exp2(x*log2e): fold into scale
  __syncthreads();                          // done reading union.sc before union.rs writes

  // --- rowsum body ---
  int ag0 = by*8 + w, ag1 = by*8 + 4 + w;
  bf16x8 a0f0 = Xb[ag0*128 + q*16 + nl];
  bf16x8 a0f1 = Xb[ag0*128 + (4+q)*16 + nl];
  bf16x8 a1f0 = Xb[ag1*128 + q*16 + nl];
  bf16x8 a1f1 = Xb[ag1*128 + (4+q)*16 + nl];
  float ga0 = Gz[ag0*16 + nl], ga1 = Gz[ag1*16 + nl];
  float g0m[4], g1m[4];
#pragma unroll
  for (int r=0;r<4;r++){ g0m[r] = __shfl(ga0, q*4+r, 64); g1m[r] = __shfl(ga1, q*4+r, 64); }
  float rs0[4] = {0,0,0,0}, rs1[4] = {0,0,0,0};
#pragma unroll
  for (int tb=0;tb<8;tb++){
    bf16x8 bf0 = sB[tb*128 + q*16 + nl];
    bf16x8 bf1 = sB[tb*128 + (4+q)*16 + nl];
    f32x4 acc0 = (f32x4)0.0f, acc1 = (f32x4)0.0f;
    acc0 = __builtin_amdgcn_mfma_f32_16x16x32_bf16(a0f0, bf0, acc0, 0,0,0);
    acc0 = __builtin_amdgcn_mfma_f32_16x16x32_bf16(a0f1, bf1, acc0, 0,0,0);
    acc1 = __builtin_amdgcn_mfma_f32_16x16x32_bf16(a1f0, bf0, acc1, 0,0,0);
    acc1 = __builtin_amdgcn_mfma_f32_16x16x32_bf16(a1f1, bf1, acc1, 0,0,0);
    int j = (bx*8 + tb)*16 + nl;
    float gb = sG[tb*16 + nl];
    float cs = 0.f;
#pragma unroll
    for (int r=0;r<4;r++){
      float d0 = (g0m[r] + gb) - 2.0f*acc0[r];
      float d1 = (g1m[r] + gb) - 2.0f*acc1[r];
      if (isdiag){
        if (ag0*16 + q*4 + r == j) d0 = 0.f;    // exact K_ii = 1
        if (ag1*16 + q*4 + r == j) d1 = 0.f;
      }
      float e0 = fexp2(d0*negi);
      float e1 = fexp2(d1*negi);
      rs0[r] += e0; rs1[r] += e1;
      cs += e0 + e1;
    }
    cs += __shfl_xor(cs, 16, 64);
    cs += __shfl_xor(cs, 32, 64);
    if (q==0) sh.rs.colLDS[w][tb*16 + nl] = (double)cs;
  }
#pragma unroll
  for (int r=0;r<4;r++){
    float v0 = rs0[r], v1 = rs1[r];
    v0 += __shfl_xor(v0,1,64); v0 += __shfl_xor(v0,2,64);
    v0 += __shfl_xor(v0,4,64); v0 += __shfl_xor(v0,8,64);
    v1 += __shfl_xor(v1,1,64); v1 += __shfl_xor(v1,2,64);
    v1 += __shfl_xor(v1,4,64); v1 += __shfl_xor(v1,8,64);
    rs0[r] = v0; rs1[r] = v1;
  }
  if (nl==0){
#pragma unroll
    for (int r=0;r<4;r++){
      sh.rs.rowacc[w*16 + q*4 + r]     = (double)rs0[r];
      sh.rs.rowacc[(4+w)*16 + q*4 + r] = (double)rs1[r];
    }
  }
  __syncthreads();
  double tot = 0.0;
  if (tid < 128){
    double rv = sh.rs.rowacc[tid];
    double cv = sh.rs.colLDS[0][tid] + sh.rs.colLDS[1][tid] + sh.rs.colLDS[2][tid] + sh.rs.colLDS[3][tid];
    double* rowG = z ? rowL : rowK;
    atomicAdd(&rowG[by*128 + tid], rv);
    if (!isdiag) atomicAdd(&rowG[bx*128 + tid], cv);
    tot = rv + (isdiag ? 0.0 : cv);
  }
#pragma unroll
  for (int s2=1;s2<64;s2<<=1) tot += __shfl_xor(tot, s2, 64);
  if (lane==0 && w<2) sh.rs.tred[w] = tot;
  __syncthreads();
  if (tid==0) atomicAdd(&sumsS[z*8 + (blockIdx.x & 7)], sh.rs.tred[0] + sh.rs.tred[1]);
}

// ---------- block-parallel gamma series: 2048 terms/batch (8 per thread) ----------
// termination 1e-13: residual tail far below f32 output needs
__device__ double gammainc_block8(double a, double x, double lga,
                                  int tid, int lane, int w,
                                  double* wp /*shared[4]*/, double* bs /*shared[4]*/){
  double C = 1.0/a;
  double psum = 0.0;
  for (int b=0;b<256;b++){
    double k0 = (double)(b*2048 + tid*8);
    double r1 = x/(a+k0+1.0), r2 = x/(a+k0+2.0), r3 = x/(a+k0+3.0), r4 = x/(a+k0+4.0);
    double r5 = x/(a+k0+5.0), r6 = x/(a+k0+6.0), r7 = x/(a+k0+7.0), r8 = x/(a+k0+8.0);
    double p12 = r1*r2, p34 = r3*r4, p56 = r5*r6, p78 = r7*r8;
    double p14 = p12*p34, p58 = p56*p78;
    double pl = p14*p58;                   // product of this thread's 8 ratios
    double pp = pl;                        // inclusive prefix across 64 lanes
#pragma unroll
    for (int s=1;s<64;s<<=1){
      double t = __shfl_up(pp, s, 64);
      if (lane >= s) pp *= t;
    }
    if (lane==63) wp[w] = pp;
    __syncthreads();
    double cross = 1.0;
    for (int k2=0;k2<w;k2++) cross *= wp[k2];
    double call = wp[0]*wp[1]*wp[2]*wp[3];
    double excl = __shfl_up(pp, 1, 64);
    if (lane==0) excl = 1.0;
    double base = C*cross*excl;            // prefix before this thread's 8 terms
    double t1 = base*r1, t2 = base*p12, t3 = t2*r3, t4 = base*p14;
    double t5 = t4*r5, t6 = t4*p56, t7 = t6*r7, t8 = base*pl;
    psum += ((t1+t2)+(t3+t4)) + ((t5+t6)+(t7+t8));
    double Cn = C*call;
    C = Cn;
    double rlast = x/(a + (double)(b*2048 + 2048));
    __syncthreads();                       // wp reused next iteration
    if (rlast < 1.0 && Cn*rlast/(1.0-rlast) < 1e-13) break;
  }
#pragma unroll
  for (int s=1;s<64;s<<=1) psum += __shfl_xor(psum, s, 64);
  if (lane==0) bs[w] = psum;
  __syncthreads();
  double total = 1.0/a + bs[0]+bs[1]+bs[2]+bs[3];
  __syncthreads();
  return exp(-x + a*log(x) - lga) * total;
}

// ---------- dispatch 4: centered products (1056 half-tile blocks) + tail finalize ----------
// (256,4): f32 body should fit 128 VGPR now (R5's spill was the f64-heavy body; since R7/R10 the
// inner loop is pure f32 with no in-loop global/f64 ops). LDS ~36 KB still allows 4 blocks/CU.
// Spill tripwire: if WRITE_SIZE explodes next profile, revert to (256,3).
__global__ __launch_bounds__(256,4) void final_k(const u16* __restrict__ Xbf, const float* __restrict__ Gall,
                                                 const float* __restrict__ scal,
                                                 const double* __restrict__ rowK,
                                                 const double* __restrict__ rowL,
                                                 const double* __restrict__ sumsS,
                                                 double* __restrict__ slotbuf, u32* __restrict__ ctr,
                                                 float* __restrict__ out){
  __shared__ bf16x8 sBX[1024];              // 16 KB: X B-panel
  __shared__ bf16x8 sBY[1024];              // 16 KB: Y B-panel
  __shared__ float sGX[128], sGY[128];      // B-panel norms
  __shared__ float scmK[128], scmL[128];    // centered col means (f32, precomputed once)
  __shared__ float sRmK[64], sRmL[64];      // A-side row means (staged once, was 16x-redundant f64 loads)
  __shared__ double red[4][3];
  __shared__ double gwp[4], gbs[4], stot[3];
  __shared__ int lastFlag;
  int tid = threadIdx.x;
  int b = blockIdx.x >> 1, half = blockIdx.x & 1;
  int by,bx; bmap(b,by,bx);
  bool isdiag = (by==bx);
  int w=tid>>6, lane=tid&63, q=lane>>4, nl=lane&15;
  const bf16x8* Xb = (const bf16x8*)Xbf;
  const bf16x8* Yb = Xb + 32768;
  const bf16x8* srcBX = Xb + (size_t)(bx*8)*128;
  const bf16x8* srcBY = Yb + (size_t)(bx*8)*128;
  for (int t=tid;t<1024;t+=256){ sBX[t] = srcBX[t]; sBY[t] = srcBY[t]; }
  const float* Gx = Gall;
  const float* Gy = Gall + NPTS;
  const double inv_n = 1.0/(double)NPTS;
  double sK=0.0, sL=0.0;
#pragma unroll
  for (int k2=0;k2<8;k2++){ sK += sumsS[k2]; sL += sumsS[8+k2]; }
  double tmK = sK*(inv_n*inv_n), tmL = sL*(inv_n*inv_n);
  if (tid < 128){
    int j = bx*128 + tid;
    sGX[tid] = Gx[j];
    sGY[tid] = Gy[j];
    scmK[tid] = (float)(rowK[j]*inv_n - tmK);   // f64 difference (cancellation-safe), then f32
    scmL[tid] = (float)(rowL[j]*inv_n - tmL);
  } else if (tid < 192){
    int lr = tid - 128;                     // local A row 0..63
    int i = by*128 + half*64 + lr;
    sRmK[lr] = (float)(rowK[i]*inv_n);
    sRmL[lr] = (float)(rowL[i]*inv_n);
  }
  float negx = -LOG2E/scal[0], negy = -LOG2E/scal[1];   // exp2-folded
  float S1f=0.f, S2f=0.f, trVf=0.f;        // f32 per-thread partials (<=32 terms)
  int ag = by*8 + half*4 + w;              // this block's 4 A row-groups
  bf16x8 axf0 = Xb[ag*128 + q*16 + nl];
  bf16x8 axf1 = Xb[ag*128 + (4+q)*16 + nl];
  bf16x8 ayf0 = Yb[ag*128 + q*16 + nl];
  bf16x8 ayf1 = Yb[ag*128 + (4+q)*16 + nl];
  float gaX = Gx[ag*16 + nl], gaY = Gy[ag*16 + nl];
  float gXm[4], gYm[4];
#pragma unroll
  for (int r=0;r<4;r++){ gXm[r] = __shfl(gaX, q*4+r, 64); gYm[r] = __shfl(gaY, q*4+r, 64); }
  __syncthreads();                          // panels + G/cm/rm staged
  float rmKi[4], rmLi[4];
#pragma unroll
  for (int r=0;r<4;r++){
    int lr = w*16 + q*4 + r;
    rmKi[r] = sRmK[lr]; rmLi[r] = sRmL[lr];
  }
#pragma unroll
  for (int tb=0;tb<8;tb++){
    bf16x8 bx0 = sBX[tb*128 + q*16 + nl];
    bf16x8 bx1 = sBX[tb*128 + (4+q)*16 + nl];
    bf16x8 by0 = sBY[tb*128 + q*16 + nl];
    bf16x8 by1 = sBY[tb*128 + (4+q)*16 + nl];
    f32x4 accX = (f32x4)0.0f, accY = (f32x4)0.0f;
    accX = __builtin_amdgcn_mfma_f32_16x16x32_bf16(axf0, bx0, accX, 0,0,0);
    accX = __builtin_amdgcn_mfma_f32_16x16x32_bf16(axf1, bx1, accX, 0,0,0);
    accY = __builtin_amdgcn_mfma_f32_16x16x32_bf16(ayf0, by0, accY, 0,0,0);
    accY = __builtin_amdgcn_mfma_f32_16x16x32_bf16(ayf1, by1, accY, 0,0,0);
    int jj = tb*16 + nl;
    int j = bx*128 + jj;
    float gbX = sGX[jj], gbY = sGY[jj];
    float cmK = scmK[jj], cmL = scmL[jj];
#pragma unroll
    for (int r=0;r<4;r++){
      int i = ag*16 + q*4 + r;
      float dx = (gXm[r] + gbX) - 2.0f*accX[r];
      float dy = (gYm[r] + gbY) - 2.0f*accY[r];
      bool dg = isdiag && i==j;
      if (dg){ dx = 0.f; dy = 0.f; }
      float kx = fexp2(dx*negx);
      float lv = fexp2(dy*negy);
      float kc = (kx - rmKi[r]) - cmK;
      float lc = (lv - rmLi[r]) - cmL;
      float prod = kc*lc;
      S1f += prod;
      S2f = fmaf(prod, prod, S2f);
      if (dg) trVf = fmaf(prod, prod, trVf);
    }
  }
  double S1, S2, trV;
  {
    double wgt = isdiag ? 1.0 : 2.0;
    S1 = (double)S1f * wgt;
    S2 = (double)S2f * (wgt*(1.0/36.0));
    trV = (double)trVf * (1.0/36.0);
  }
  double vals[3]={S1,S2,trV};
#pragma unroll
  for (int v=0;v<3;v++){
    double x = vals[v];
#pragma unroll
    for (int s2=1;s2<64;s2<<=1) x += __shfl_xor(x, s2, 64);
    if (lane==0) red[w][v]=x;
  }
  __syncthreads();
  if (tid < 3){
    double val = red[0][tid]+red[1][tid]+red[2][tid]+red[3][tid];
    // returning atomic: completion (not just issue) before the barrier's vmcnt drain
    double old = atomicAdd(&slotbuf[(size_t)(blockIdx.x & 15)*4 + tid], val);
    asm volatile("" :: "v"(old));          // keep the return value live
  }
  __syncthreads();                          // drains vmcnt: slot adds complete before ctr bump
  if (tid==0){
    u32 old = atomicAdd(ctr, 1u);
    lastFlag = (old == (u32)(2*NBLK - 1)) ? 1 : 0;
  }
  __syncthreads();
  if (!lastFlag) return;

  // ---- tail block (all 256 threads): reduce slots + gamma-ppf ----
  if (w==0){
    double t0=0.0, t1=0.0, t2=0.0;
    if (lane < 16){
      double* sp = slotbuf + (size_t)lane*4;
      t0 = atomicAdd(&sp[0], 0.0);   // atomic RMW read: coherent across XCD L2s
      t1 = atomicAdd(&sp[1], 0.0);
      t2 = atomicAdd(&sp[2], 0.0);
    }
#pragma unroll
    for (int s2=1;s2<16;s2<<=1){
      t0 += __shfl_xor(t0, s2, 64);
      t1 += __shfl_xor(t1, s2, 64);
      t2 += __shfl_xor(t2, s2, 64);
    }
    if (lane==0){ stot[0]=t0; stot[1]=t1; stot[2]=t2; }
  }
  __syncthreads();
  const double n = (double)NPTS;
  double S1t=stot[0], S2t=stot[1], trVt=stot[2];
  double testStat = S1t/n;
  double varHSIC = (S2t - trVt)/n/(n-1.0);
  varHSIC = varHSIC*72.0*(n-4.0)*(n-5.0)/n/(n-1.0)/(n-2.0)/(n-3.0);
  double muX = (sK-n)/n/(n-1.0);   // trace(K) = n exactly (diag forced to 1)
  double muY = (sL-n)/n/(n-1.0);
  double mHSIC = (1.0 + muX*muY - muX - muY)/n;
  double al = mHSIC*mHSIC/varHSIC;
  double bet = varHSIC*n/mHSIC;
  double p = (double)((float)(1.0-0.8));
  double lga = lgamma(al);
  double lo = 0.0, hi = al + 10.0*sqrt(al) + 100.0;
  const double zp = -0.8416212335729142957;  // Phi^-1(0.2)
  double tt = 1.0 - 1.0/(9.0*al) + zp/(3.0*sqrt(al));
  double x = al*tt*tt*tt;
  if (!(x > 0.0) || !(x < hi)) x = 0.5*hi;
  for (int it=0; it<2; ++it){
    double P = gammainc_block8(al, x, lga, tid, lane, w, gwp, gbs);
    double diff = P - p;
    if (diff < 0.0) lo = x; else hi = x;
    if (fabs(diff) < 1e-12) break;
    double pdf = exp(-x + (al-1.0)*log(x) - lga);
    double nx = x - diff/pdf;
    if (!(nx > lo) || !(nx < hi)) nx = 0.5*(lo+hi);
    x = nx;
  }
  if (tid==0){
    out[0]=(float)testStat;
    out[1]=(float)(bet*x);
  }
}

// ---------- host ----------
extern "C" void kernel_launch(void* const* d_in, const int* in_sizes, int n_in,
                              void* d_out, int out_size, void* d_ws, size_t ws_size,
                              hipStream_t stream) {
  const float* X = (const float*)d_in[0];
  const float* Y = (const float*)d_in[1];
  float* out = (float*)d_out;
  char* ws = (char*)d_ws;

  double* sumsS    = (double*)ws;                    // 16 doubles (8 slots per z)
  float*  scal     = (float*)(ws + 128);             // 2 floats
  u32*    histsum  = (u32*)(ws + 256);               // 2*836 u32 = 6688 B
  double* slotbuf  = (double*)(ws + 7168);           // 16 slots x 4 doubles = 512 B
  u32*    ctr      = (u32*)(ws + 7680);              // done counter
  double* rowK     = (double*)(ws + 8192);           // 32 KB
  double* rowL     = (double*)(ws + 40960);          // 32 KB
  float*  Gall     = (float*)(ws + 73728);           // 32 KB
  u16*    Xbf      = (u16*)(ws + (4u<<20));          // 1 MB (swizzled fragment-major)
  size_t need = (size_t)(4u<<20) + (size_t)2*NPTS*DIM*2;   // ~5.2 MB

  if (ws_size < need) return;

  convert_k<<<128,256,0,stream>>>(X, Y, Xbf, Gall, histsum, rowK, rowL, sumsS, slotbuf, ctr);
  hist_k<<<dim3(NBLK,2),256,0,stream>>>(Xbf, Gall, histsum);
  rowsum_k<<<dim3(NBLK,2),256,0,stream>>>(Xbf, Gall, histsum, scal, rowK, rowL, sumsS);
  final_k<<<2*NBLK,256,0,stream>>>(Xbf, Gall, scal, rowK, rowL, sumsS, slotbuf, ctr, out);
}